// Round 1
// baseline (1133.955 us; speedup 1.0000x reference)
//
#include <hip/hip_runtime.h>
#include <math.h>

#define TT 2048

typedef __bf16 bf16;
typedef __bf16 bf16x8 __attribute__((ext_vector_type(8)));
typedef __bf16 bf16x4v __attribute__((ext_vector_type(4)));
typedef __bf16 bf16x2v __attribute__((ext_vector_type(2)));
typedef float f32x4 __attribute__((ext_vector_type(4)));

__device__ __forceinline__ float wredsum(float v) {
#pragma unroll
  for (int off = 32; off > 0; off >>= 1) v += __shfl_xor(v, off, 64);
  return v;
}
__device__ __forceinline__ float sigmoidf_(float x) { return 1.f / (1.f + __expf(-x)); }

// ---------------- RMSNorm: h[2048,1024] -> xf (f32), xb (bf16) ----------------
__global__ __launch_bounds__(256) void k_rmsnorm(const float* __restrict__ h,
    const float* __restrict__ nw, float* __restrict__ xf, bf16* __restrict__ xb) {
  int t = blockIdx.x, tid = threadIdx.x;
  float4 hv = *(const float4*)(h + (size_t)t*1024 + tid*4);
  float ss = hv.x*hv.x + hv.y*hv.y + hv.z*hv.z + hv.w*hv.w;
  __shared__ float red[4];
  float wsum = wredsum(ss);
  if ((tid & 63) == 0) red[tid >> 6] = wsum;
  __syncthreads();
  float tot = red[0] + red[1] + red[2] + red[3];
  float rs = rsqrtf(tot * (1.f/1024.f) + 1e-6f);
  float4 w4 = *(const float4*)(nw + tid*4);
  float4 y;
  y.x = hv.x*rs*w4.x; y.y = hv.y*rs*w4.y; y.z = hv.z*rs*w4.z; y.w = hv.w*rs*w4.w;
  *(float4*)(xf + (size_t)t*1024 + tid*4) = y;
  bf16x4v b; b[0]=(bf16)y.x; b[1]=(bf16)y.y; b[2]=(bf16)y.z; b[3]=(bf16)y.w;
  *(bf16x4v*)(xb + (size_t)t*1024 + tid*4) = b;
}

// ---------------- cast weights f32 -> bf16 (6 tensors, 9M elems) ----------------
__global__ void k_castw(const float* __restrict__ qw, const float* __restrict__ kw,
    const float* __restrict__ vw, const float* __restrict__ gw,
    const float* __restrict__ opw, const float* __restrict__ ow,
    bf16* qwb, bf16* kwb, bf16* vwb, bf16* gwb, bf16* opwb, bf16* owb) {
  // float4 unit counts: qw 262144, kw 262144, vw 524288, gw 524288, opw 524288, ow 262144
  for (long u = (long)blockIdx.x*256 + threadIdx.x; u < 2359296; u += (long)gridDim.x*256) {
    const float* src; bf16* dst; long l;
    if      (u <  262144) { src=qw;  dst=qwb;  l=u; }
    else if (u <  524288) { src=kw;  dst=kwb;  l=u-262144; }
    else if (u < 1048576) { src=vw;  dst=vwb;  l=u-524288; }
    else if (u < 1572864) { src=gw;  dst=gwb;  l=u-1048576; }
    else if (u < 2097152) { src=opw; dst=opwb; l=u-1572864; }
    else                  { src=ow;  dst=owb;  l=u-2097152; }
    float4 s = *(const float4*)(src + l*4);
    bf16x4v b; b[0]=(bf16)s.x; b[1]=(bf16)s.y; b[2]=(bf16)s.z; b[3]=(bf16)s.w;
    *(bf16x4v*)(dst + l*4) = b;
  }
}

// ---------------- bf16 MFMA GEMM: C[M,N] = A[M,K] * B[N,K]^T ----------------
// 128x128 tile, BK=32, 256 threads (4 waves 2x2 of 64x64), global_load_lds staging.
template <typename OutT>
__device__ __forceinline__ void gemm_body(const bf16* __restrict__ A,
    const bf16* __restrict__ B, OutT* __restrict__ C, int N, int K, int m0, int n0) {
  __shared__ bf16 As[128*32];
  __shared__ bf16 Bs[128*32];
  const int tid = threadIdx.x, lane = tid & 63, wave = tid >> 6;
  const int wm = (wave >> 1) * 64, wn = (wave & 1) * 64;
  const int srow = wave*16 + (lane >> 2);
  const int skk = (lane & 3) * 8;
  const int quad = lane >> 4, l16 = lane & 15;
  f32x4 acc[4][4] = {};
  for (int k0 = 0; k0 < K; k0 += 32) {
    __syncthreads();
#pragma unroll
    for (int i = 0; i < 2; ++i) {
      int r = i*64 + srow;
      __builtin_amdgcn_global_load_lds(
        (__attribute__((address_space(1))) void*)(A + (size_t)(m0 + r)*K + k0 + skk),
        (__attribute__((address_space(3))) void*)(As + r*32 + skk), 16, 0, 0);
      __builtin_amdgcn_global_load_lds(
        (__attribute__((address_space(1))) void*)(B + (size_t)(n0 + r)*K + k0 + skk),
        (__attribute__((address_space(3))) void*)(Bs + r*32 + skk), 16, 0, 0);
    }
    __syncthreads();
    bf16x8 af[4], bfr[4];
#pragma unroll
    for (int mt = 0; mt < 4; ++mt)
      af[mt] = *(const bf16x8*)(As + (wm + mt*16 + l16)*32 + quad*8);
#pragma unroll
    for (int nt = 0; nt < 4; ++nt)
      bfr[nt] = *(const bf16x8*)(Bs + (wn + nt*16 + l16)*32 + quad*8);
#pragma unroll
    for (int mt = 0; mt < 4; ++mt)
#pragma unroll
      for (int nt = 0; nt < 4; ++nt)
        acc[mt][nt] = __builtin_amdgcn_mfma_f32_16x16x32_bf16(af[mt], bfr[nt], acc[mt][nt], 0, 0, 0);
  }
#pragma unroll
  for (int mt = 0; mt < 4; ++mt)
#pragma unroll
    for (int nt = 0; nt < 4; ++nt)
#pragma unroll
      for (int r = 0; r < 4; ++r) {
        int row = m0 + wm + mt*16 + quad*4 + r;
        int col = n0 + wn + nt*16 + l16;
        C[(size_t)row*N + col] = (OutT)acc[mt][nt][r];
      }
}

// fused projection GEMM: z selects {q,k,v,g}
__global__ __launch_bounds__(256) void k_gemm_proj(const bf16* __restrict__ A,
    const bf16* __restrict__ qwb, const bf16* __restrict__ kwb,
    const bf16* __restrict__ vwb, const bf16* __restrict__ gwb,
    float* __restrict__ qpre, float* __restrict__ kpre,
    float* __restrict__ vpre, float* __restrict__ gpre) {
  int z = blockIdx.z;
  const bf16* B; float* C; int N;
  if      (z == 0) { B = qwb; C = qpre; N = 1024; }
  else if (z == 1) { B = kwb; C = kpre; N = 1024; }
  else if (z == 2) { B = vwb; C = vpre; N = 2048; }
  else             { B = gwb; C = gpre; N = 2048; }
  if ((int)blockIdx.x * 128 >= N) return;
  gemm_body<float>(A, B, C, N, 1024, blockIdx.y*128, blockIdx.x*128);
}

template <typename OutT>
__global__ __launch_bounds__(256) void k_gemm_bt(const bf16* __restrict__ A,
    const bf16* __restrict__ B, OutT* __restrict__ C, int N, int K) {
  gemm_body<OutT>(A, B, C, N, K, blockIdx.y*128, blockIdx.x*128);
}

// ---------------- a/b projections (fp32) -> exp(g), beta ----------------
__global__ __launch_bounds__(64) void k_ab(const float* __restrict__ xf,
    const float* __restrict__ aw, const float* __restrict__ bw,
    const float* __restrict__ dtb, const float* __restrict__ alog,
    float* __restrict__ eg, float* __restrict__ beta) {
  int t = blockIdx.x, lane = threadIdx.x;
  __shared__ __align__(16) float xs[1024];
#pragma unroll
  for (int i = 0; i < 16; ++i) xs[i*64 + lane] = xf[(size_t)t*1024 + i*64 + lane];
  __syncthreads();
  const float4* x4 = (const float4*)xs;
  for (int hh = 0; hh < 16; ++hh) {
    float sa = 0.f, sb = 0.f;
#pragma unroll
    for (int i = 0; i < 4; ++i) {
      float4 xv = x4[i*64 + lane];
      float4 av = *(const float4*)(aw + hh*1024 + i*256 + lane*4);
      float4 bv = *(const float4*)(bw + hh*1024 + i*256 + lane*4);
      sa += xv.x*av.x + xv.y*av.y + xv.z*av.z + xv.w*av.w;
      sb += xv.x*bv.x + xv.y*bv.y + xv.z*bv.z + xv.w*bv.w;
    }
    sa = wredsum(sa); sb = wredsum(sb);
    if (lane == 0) {
      float ap = sa + dtb[hh];
      float sp = (ap > 20.f) ? ap : log1pf(expf(ap));
      float g = -expf(alog[hh]) * sp;
      eg[t*16 + hh] = expf(g);
      beta[t*16 + hh] = 1.f / (1.f + expf(-sb));
    }
  }
}

// ---------------- conv(K=4)+silu for q,k + per-head postprocessing ----------------
__global__ __launch_bounds__(256) void k_convqk(const float* __restrict__ qpre,
    const float* __restrict__ kpre, const float* __restrict__ cqw,
    const float* __restrict__ ckw, float* __restrict__ qpost, float* __restrict__ kpost) {
  int t = blockIdx.x, cb = blockIdx.y, isk = blockIdx.z;
  int c = cb*256 + threadIdx.x;
  const float* in = isk ? kpre : qpre;
  const float* w  = isk ? ckw : cqw;
  float4 wv = *(const float4*)(w + c*4);
  float y = 0.f;
  int tt = t - 3;
  if (tt     >= 0) y += in[(size_t)(tt  )*1024 + c] * wv.x;
  if (tt + 1 >= 0) y += in[(size_t)(tt+1)*1024 + c] * wv.y;
  if (tt + 2 >= 0) y += in[(size_t)(tt+2)*1024 + c] * wv.z;
  y += in[(size_t)t*1024 + c] * wv.w;
  y = y * sigmoidf_(y);   // silu
  if (isk) {
    float m = wredsum(y) * (1.f/64.f);   // rank-1 DC removal (per-head mean, DK=64=wave)
    y -= m;
    float ss = wredsum(y*y);
    y *= rsqrtf(ss + 1e-6f);
    kpost[(size_t)t*1024 + c] = y;
  } else {
    float ss = wredsum(y*y);
    y *= rsqrtf(ss + 1e-6f) * 0.125f;    // * DK^-0.5
    qpost[(size_t)t*1024 + c] = y;
  }
}

// ---------------- conv(K=4)+silu for v ----------------
__global__ __launch_bounds__(256) void k_convv(const float* __restrict__ vpre,
    const float* __restrict__ cvw, float* __restrict__ vpost) {
  int t = blockIdx.x;
  int c0 = blockIdx.y*1024 + threadIdx.x*4;
  float a0=0.f, a1=0.f, a2=0.f, a3=0.f;
#pragma unroll
  for (int i = 0; i < 4; ++i) {
    int tt = t - 3 + i;
    if (tt < 0) continue;
    float4 in4 = *(const float4*)(vpre + (size_t)tt*2048 + c0);
    a0 += in4.x * cvw[(c0+0)*4 + i];
    a1 += in4.y * cvw[(c0+1)*4 + i];
    a2 += in4.z * cvw[(c0+2)*4 + i];
    a3 += in4.w * cvw[(c0+3)*4 + i];
  }
  float4 o4;
  o4.x = a0 * sigmoidf_(a0); o4.y = a1 * sigmoidf_(a1);
  o4.z = a2 * sigmoidf_(a2); o4.w = a3 * sigmoidf_(a3);
  *(float4*)(vpost + (size_t)t*2048 + c0) = o4;
}

// ---------------- gated delta-rule scan ----------------
// grid 64: (head = bx>>2, colgroup = bx&3, 32 cols each). 256 thr: 8 lanes/col.
__global__ __launch_bounds__(256) void k_scan(const float* __restrict__ q,
    const float* __restrict__ k, const float* __restrict__ v,
    const float* __restrict__ eg, const float* __restrict__ bt,
    float* __restrict__ o) {
  const int hh = blockIdx.x >> 2, cg = blockIdx.x & 3;
  const int tid = threadIdx.x;
  const int col = cg*32 + (tid >> 3), sub = tid & 7;
  __shared__ float egs[TT], bts[TT];
  for (int i = tid; i < TT; i += 256) {
    egs[i] = eg[i*16 + hh];
    bts[i] = bt[i*16 + hh];
  }
  __syncthreads();
  float s0=0,s1=0,s2=0,s3=0,s4=0,s5=0,s6=0,s7=0;
  const float* kp = k + hh*64 + sub*8;
  const float* qp = q + hh*64 + sub*8;
  const float* vp = v + hh*128 + col;
  float*       op = o + hh*128 + col;
  float4 ka = *(const float4*)kp;
  float4 kb = *(const float4*)(kp + 4);
  float4 qa = *(const float4*)qp;
  float4 qb = *(const float4*)(qp + 4);
  float vv = *vp;
  for (int t = 0; t < TT; ++t) {
    int tn = (t + 1) & (TT - 1);       // wraps to 0 on last iter; values unused
    float4 kna = *(const float4*)(kp + (size_t)tn*1024);
    float4 knb = *(const float4*)(kp + (size_t)tn*1024 + 4);
    float4 qna = *(const float4*)(qp + (size_t)tn*1024);
    float4 qnb = *(const float4*)(qp + (size_t)tn*1024 + 4);
    float  vn  = vp[(size_t)tn*2048];
    float egv = egs[t], btv = bts[t];
    float ks = ka.x*s0 + ka.y*s1 + ka.z*s2 + ka.w*s3
             + kb.x*s4 + kb.y*s5 + kb.z*s6 + kb.w*s7;
    ks += __shfl_xor(ks, 1, 64);
    ks += __shfl_xor(ks, 2, 64);
    ks += __shfl_xor(ks, 4, 64);
    float vnew = (vv - egv*ks) * btv;
    s0 = egv*s0 + ka.x*vnew; s1 = egv*s1 + ka.y*vnew;
    s2 = egv*s2 + ka.z*vnew; s3 = egv*s3 + ka.w*vnew;
    s4 = egv*s4 + kb.x*vnew; s5 = egv*s5 + kb.y*vnew;
    s6 = egv*s6 + kb.z*vnew; s7 = egv*s7 + kb.w*vnew;
    float oo = qa.x*s0 + qa.y*s1 + qa.z*s2 + qa.w*s3
             + qb.x*s4 + qb.y*s5 + qb.z*s6 + qb.w*s7;
    oo += __shfl_xor(oo, 1, 64);
    oo += __shfl_xor(oo, 2, 64);
    oo += __shfl_xor(oo, 4, 64);
    if (sub == 0) op[(size_t)t*2048] = oo;
    ka = kna; kb = knb; qa = qna; qb = qnb; vv = vn;
  }
}

// ---------------- gated RMSNorm on o, write bf16 ----------------
__global__ __launch_bounds__(64) void k_gatenorm(const float* __restrict__ o,
    const float* __restrict__ gpre, const float* __restrict__ onw,
    bf16* __restrict__ og) {
  int t = blockIdx.x, hh = blockIdx.y, lane = threadIdx.x;
  const float* obase = o + (size_t)t*2048 + hh*128;
  float2 o2 = *(const float2*)(obase + lane*2);
  float ss = wredsum(o2.x*o2.x + o2.y*o2.y);
  float rs = rsqrtf(ss * (1.f/128.f) + 1e-5f);
  float2 nw = *(const float2*)(onw + lane*2);
  float2 g2 = *(const float2*)(gpre + (size_t)t*2048 + hh*128 + lane*2);
  float r0 = o2.x * rs * nw.x * (g2.x * sigmoidf_(g2.x));
  float r1 = o2.y * rs * nw.y * (g2.y * sigmoidf_(g2.y));
  bf16x2v b; b[0] = (bf16)r0; b[1] = (bf16)r1;
  *(bf16x2v*)(og + (size_t)t*2048 + hh*128 + lane*2) = b;
}

extern "C" void kernel_launch(void* const* d_in, const int* in_sizes, int n_in,
                              void* d_out, int out_size, void* d_ws, size_t ws_size,
                              hipStream_t stream) {
  const float* hs   = (const float*)d_in[0];
  const float* nw   = (const float*)d_in[1];
  const float* qw   = (const float*)d_in[2];
  const float* kw   = (const float*)d_in[3];
  const float* vw   = (const float*)d_in[4];
  const float* aw   = (const float*)d_in[5];
  const float* bw   = (const float*)d_in[6];
  const float* gw   = (const float*)d_in[7];
  const float* dtb  = (const float*)d_in[8];
  const float* alog = (const float*)d_in[9];
  const float* cqw  = (const float*)d_in[10];
  const float* ckw  = (const float*)d_in[11];
  const float* cvw  = (const float*)d_in[12];
  const float* onw  = (const float*)d_in[13];
  const float* opw  = (const float*)d_in[14];
  const float* ow   = (const float*)d_in[15];
  float* out = (float*)d_out;

  char* p = (char*)d_ws;
  auto alloc = [&](size_t bytes) { char* r = p; p += (bytes + 255) & ~255ull; return r; };
  float* xf    = (float*)alloc((size_t)2048*1024*4);
  bf16*  xb    = (bf16*) alloc((size_t)2048*1024*2);
  bf16*  qwb   = (bf16*) alloc((size_t)1024*1024*2);
  bf16*  kwb   = (bf16*) alloc((size_t)1024*1024*2);
  bf16*  vwb   = (bf16*) alloc((size_t)2048*1024*2);
  bf16*  gwb   = (bf16*) alloc((size_t)2048*1024*2);
  bf16*  opwb  = (bf16*) alloc((size_t)1024*2048*2);
  bf16*  owb   = (bf16*) alloc((size_t)1024*1024*2);
  float* qpre  = (float*)alloc((size_t)2048*1024*4);
  float* kpre  = (float*)alloc((size_t)2048*1024*4);
  float* vpre  = (float*)alloc((size_t)2048*2048*4);
  float* gpre  = (float*)alloc((size_t)2048*2048*4);
  float* qpost = (float*)alloc((size_t)2048*1024*4);
  float* kpost = (float*)alloc((size_t)2048*1024*4);
  float* vpost = (float*)alloc((size_t)2048*2048*4);
  float* egb   = (float*)alloc((size_t)2048*16*4);
  float* btb   = (float*)alloc((size_t)2048*16*4);
  float* ob    = (float*)alloc((size_t)2048*2048*4);
  bf16*  ogb   = (bf16*) alloc((size_t)2048*2048*2);
  bf16*  h1b   = (bf16*) alloc((size_t)2048*1024*2);

  k_rmsnorm<<<2048, 256, 0, stream>>>(hs, nw, xf, xb);
  k_castw<<<4608, 256, 0, stream>>>(qw, kw, vw, gw, opw, ow, qwb, kwb, vwb, gwb, opwb, owb);
  k_gemm_proj<<<dim3(16,16,4), 256, 0, stream>>>(xb, qwb, kwb, vwb, gwb, qpre, kpre, vpre, gpre);
  k_ab<<<2048, 64, 0, stream>>>(xf, aw, bw, dtb, alog, egb, btb);
  k_convqk<<<dim3(2048,4,2), 256, 0, stream>>>(qpre, kpre, cqw, ckw, qpost, kpost);
  k_convv<<<dim3(2048,2,1), 256, 0, stream>>>(vpre, cvw, vpost);
  k_scan<<<64, 256, 0, stream>>>(qpost, kpost, vpost, egb, btb, ob);
  k_gatenorm<<<dim3(2048,16,1), 64, 0, stream>>>(ob, gpre, onw, ogb);
  k_gemm_bt<bf16><<<dim3(8,16,1), 256, 0, stream>>>(ogb, opwb, h1b, 1024, 2048);
  k_gemm_bt<float><<<dim3(8,16,1), 256, 0, stream>>>(h1b, owb, out, 1024, 1024);
}

// Round 2
// 898.761 us; speedup vs baseline: 1.2617x; 1.2617x over previous
//
#include <hip/hip_runtime.h>
#include <math.h>

#define TT 2048

typedef __bf16 bf16;
typedef __bf16 bf16x8 __attribute__((ext_vector_type(8)));
typedef __bf16 bf16x4v __attribute__((ext_vector_type(4)));
typedef __bf16 bf16x2v __attribute__((ext_vector_type(2)));
typedef float f32x4 __attribute__((ext_vector_type(4)));

__device__ __forceinline__ float wredsum(float v) {
#pragma unroll
  for (int off = 32; off > 0; off >>= 1) v += __shfl_xor(v, off, 64);
  return v;
}
__device__ __forceinline__ float sigmoidf_(float x) { return 1.f / (1.f + __expf(-x)); }

// ---------------- RMSNorm: h[2048,1024] -> xf (f32), xb (bf16) ----------------
__global__ __launch_bounds__(256) void k_rmsnorm(const float* __restrict__ h,
    const float* __restrict__ nw, float* __restrict__ xf, bf16* __restrict__ xb) {
  int t = blockIdx.x, tid = threadIdx.x;
  float4 hv = *(const float4*)(h + (size_t)t*1024 + tid*4);
  float ss = hv.x*hv.x + hv.y*hv.y + hv.z*hv.z + hv.w*hv.w;
  __shared__ float red[4];
  float wsum = wredsum(ss);
  if ((tid & 63) == 0) red[tid >> 6] = wsum;
  __syncthreads();
  float tot = red[0] + red[1] + red[2] + red[3];
  float rs = rsqrtf(tot * (1.f/1024.f) + 1e-6f);
  float4 w4 = *(const float4*)(nw + tid*4);
  float4 y;
  y.x = hv.x*rs*w4.x; y.y = hv.y*rs*w4.y; y.z = hv.z*rs*w4.z; y.w = hv.w*rs*w4.w;
  *(float4*)(xf + (size_t)t*1024 + tid*4) = y;
  bf16x4v b; b[0]=(bf16)y.x; b[1]=(bf16)y.y; b[2]=(bf16)y.z; b[3]=(bf16)y.w;
  *(bf16x4v*)(xb + (size_t)t*1024 + tid*4) = b;
}

// ---------------- cast weights f32 -> bf16 (6 tensors) ----------------
__global__ void k_castw(const float* __restrict__ qw, const float* __restrict__ kw,
    const float* __restrict__ vw, const float* __restrict__ gw,
    const float* __restrict__ opw, const float* __restrict__ ow,
    bf16* qwb, bf16* kwb, bf16* vwb, bf16* gwb, bf16* opwb, bf16* owb) {
  for (long u = (long)blockIdx.x*256 + threadIdx.x; u < 2359296; u += (long)gridDim.x*256) {
    const float* src; bf16* dst; long l;
    if      (u <  262144) { src=qw;  dst=qwb;  l=u; }
    else if (u <  524288) { src=kw;  dst=kwb;  l=u-262144; }
    else if (u < 1048576) { src=vw;  dst=vwb;  l=u-524288; }
    else if (u < 1572864) { src=gw;  dst=gwb;  l=u-1048576; }
    else if (u < 2097152) { src=opw; dst=opwb; l=u-1572864; }
    else                  { src=ow;  dst=owb;  l=u-2097152; }
    float4 s = *(const float4*)(src + l*4);
    bf16x4v b; b[0]=(bf16)s.x; b[1]=(bf16)s.y; b[2]=(bf16)s.z; b[3]=(bf16)s.w;
    *(bf16x4v*)(dst + l*4) = b;
  }
}

// ---------------- bf16 MFMA GEMM: C[M,N] = A[M,K] * B[N,K]^T ----------------
template <typename OutT>
__device__ __forceinline__ void gemm_body(const bf16* __restrict__ A,
    const bf16* __restrict__ B, OutT* __restrict__ C, int N, int K, int m0, int n0) {
  __shared__ bf16 As[128*32];
  __shared__ bf16 Bs[128*32];
  const int tid = threadIdx.x, lane = tid & 63, wave = tid >> 6;
  const int wm = (wave >> 1) * 64, wn = (wave & 1) * 64;
  const int srow = wave*16 + (lane >> 2);
  const int skk = (lane & 3) * 8;
  const int quad = lane >> 4, l16 = lane & 15;
  f32x4 acc[4][4] = {};
  for (int k0 = 0; k0 < K; k0 += 32) {
    __syncthreads();
#pragma unroll
    for (int i = 0; i < 2; ++i) {
      int r = i*64 + srow;
      __builtin_amdgcn_global_load_lds(
        (__attribute__((address_space(1))) void*)(A + (size_t)(m0 + r)*K + k0 + skk),
        (__attribute__((address_space(3))) void*)(As + r*32 + skk), 16, 0, 0);
      __builtin_amdgcn_global_load_lds(
        (__attribute__((address_space(1))) void*)(B + (size_t)(n0 + r)*K + k0 + skk),
        (__attribute__((address_space(3))) void*)(Bs + r*32 + skk), 16, 0, 0);
    }
    __syncthreads();
    bf16x8 af[4], bfr[4];
#pragma unroll
    for (int mt = 0; mt < 4; ++mt)
      af[mt] = *(const bf16x8*)(As + (wm + mt*16 + l16)*32 + quad*8);
#pragma unroll
    for (int nt = 0; nt < 4; ++nt)
      bfr[nt] = *(const bf16x8*)(Bs + (wn + nt*16 + l16)*32 + quad*8);
#pragma unroll
    for (int mt = 0; mt < 4; ++mt)
#pragma unroll
      for (int nt = 0; nt < 4; ++nt)
        acc[mt][nt] = __builtin_amdgcn_mfma_f32_16x16x32_bf16(af[mt], bfr[nt], acc[mt][nt], 0, 0, 0);
  }
#pragma unroll
  for (int mt = 0; mt < 4; ++mt)
#pragma unroll
    for (int nt = 0; nt < 4; ++nt)
#pragma unroll
      for (int r = 0; r < 4; ++r) {
        int row = m0 + wm + mt*16 + quad*4 + r;
        int col = n0 + wn + nt*16 + l16;
        C[(size_t)row*N + col] = (OutT)acc[mt][nt][r];
      }
}

__global__ __launch_bounds__(256) void k_gemm_proj(const bf16* __restrict__ A,
    const bf16* __restrict__ qwb, const bf16* __restrict__ kwb,
    const bf16* __restrict__ vwb, const bf16* __restrict__ gwb,
    float* __restrict__ qpre, float* __restrict__ kpre,
    float* __restrict__ vpre, float* __restrict__ gpre) {
  int z = blockIdx.z;
  const bf16* B; float* C; int N;
  if      (z == 0) { B = qwb; C = qpre; N = 1024; }
  else if (z == 1) { B = kwb; C = kpre; N = 1024; }
  else if (z == 2) { B = vwb; C = vpre; N = 2048; }
  else             { B = gwb; C = gpre; N = 2048; }
  if ((int)blockIdx.x * 128 >= N) return;
  gemm_body<float>(A, B, C, N, 1024, blockIdx.y*128, blockIdx.x*128);
}

template <typename OutT>
__global__ __launch_bounds__(256) void k_gemm_bt(const bf16* __restrict__ A,
    const bf16* __restrict__ B, OutT* __restrict__ C, int N, int K) {
  gemm_body<OutT>(A, B, C, N, K, blockIdx.y*128, blockIdx.x*128);
}

// ---------------- a/b projections (fp32) -> g (log decay), beta ----------------
__global__ __launch_bounds__(64) void k_ab(const float* __restrict__ xf,
    const float* __restrict__ aw, const float* __restrict__ bw,
    const float* __restrict__ dtb, const float* __restrict__ alog,
    float* __restrict__ graw, float* __restrict__ beta) {
  int t = blockIdx.x, lane = threadIdx.x;
  __shared__ __align__(16) float xs[1024];
#pragma unroll
  for (int i = 0; i < 16; ++i) xs[i*64 + lane] = xf[(size_t)t*1024 + i*64 + lane];
  __syncthreads();
  const float4* x4 = (const float4*)xs;
  for (int hh = 0; hh < 16; ++hh) {
    float sa = 0.f, sb = 0.f;
#pragma unroll
    for (int i = 0; i < 4; ++i) {
      float4 xv = x4[i*64 + lane];
      float4 av = *(const float4*)(aw + hh*1024 + i*256 + lane*4);
      float4 bv = *(const float4*)(bw + hh*1024 + i*256 + lane*4);
      sa += xv.x*av.x + xv.y*av.y + xv.z*av.z + xv.w*av.w;
      sb += xv.x*bv.x + xv.y*bv.y + xv.z*bv.z + xv.w*bv.w;
    }
    sa = wredsum(sa); sb = wredsum(sb);
    if (lane == 0) {
      float ap = sa + dtb[hh];
      float sp = (ap > 20.f) ? ap : log1pf(expf(ap));
      graw[t*16 + hh] = -expf(alog[hh]) * sp;
      beta[t*16 + hh] = 1.f / (1.f + expf(-sb));
    }
  }
}

// ---------------- conv(K=4)+silu for q,k + per-head postprocessing ----------------
__global__ __launch_bounds__(256) void k_convqk(const float* __restrict__ qpre,
    const float* __restrict__ kpre, const float* __restrict__ cqw,
    const float* __restrict__ ckw, float* __restrict__ qpost, float* __restrict__ kpost) {
  int t = blockIdx.x, cb = blockIdx.y, isk = blockIdx.z;
  int c = cb*256 + threadIdx.x;
  const float* in = isk ? kpre : qpre;
  const float* w  = isk ? ckw : cqw;
  float4 wv = *(const float4*)(w + c*4);
  float y = 0.f;
  int tt = t - 3;
  if (tt     >= 0) y += in[(size_t)(tt  )*1024 + c] * wv.x;
  if (tt + 1 >= 0) y += in[(size_t)(tt+1)*1024 + c] * wv.y;
  if (tt + 2 >= 0) y += in[(size_t)(tt+2)*1024 + c] * wv.z;
  y += in[(size_t)t*1024 + c] * wv.w;
  y = y * sigmoidf_(y);
  if (isk) {
    float m = wredsum(y) * (1.f/64.f);
    y -= m;
    float ss = wredsum(y*y);
    y *= rsqrtf(ss + 1e-6f);
    kpost[(size_t)t*1024 + c] = y;
  } else {
    float ss = wredsum(y*y);
    y *= rsqrtf(ss + 1e-6f) * 0.125f;
    qpost[(size_t)t*1024 + c] = y;
  }
}

// ---------------- conv(K=4)+silu for v ----------------
__global__ __launch_bounds__(256) void k_convv(const float* __restrict__ vpre,
    const float* __restrict__ cvw, float* __restrict__ vpost) {
  int t = blockIdx.x;
  int c0 = blockIdx.y*1024 + threadIdx.x*4;
  float a0=0.f, a1=0.f, a2=0.f, a3=0.f;
#pragma unroll
  for (int i = 0; i < 4; ++i) {
    int tt = t - 3 + i;
    if (tt < 0) continue;
    float4 in4 = *(const float4*)(vpre + (size_t)tt*2048 + c0);
    a0 += in4.x * cvw[(c0+0)*4 + i];
    a1 += in4.y * cvw[(c0+1)*4 + i];
    a2 += in4.z * cvw[(c0+2)*4 + i];
    a3 += in4.w * cvw[(c0+3)*4 + i];
  }
  float4 o4;
  o4.x = a0 * sigmoidf_(a0); o4.y = a1 * sigmoidf_(a1);
  o4.z = a2 * sigmoidf_(a2); o4.w = a3 * sigmoidf_(a3);
  *(float4*)(vpost + (size_t)t*2048 + c0) = o4;
}

// ---------------- chunked delta-rule: parallel pre-pass ----------------
// grid 512 = 32 chunks x 16 heads, 512 threads.
// Per chunk-head computes (all fp32):
//   b_t  = cumsum(g), Gamma_t = exp(b_t)
//   A[t,s] = beta_t exp(b_t-b_s)(k_t.k_s), s<t
//   [V_loc | T2] = (I+A)^-1 [beta*V | diag(beta*Gamma)]   (forward substitution)
//   P[t,s] = exp(b_t-b_s)(q_t.k_s), s<=t
//   Kbar[s] = exp(b_C - b_s) k_s
//   E = Gamma_C I - (Kbar^T T2) K      -> Eb   (seq transition)
//   dS_loc = Kbar^T V_loc              -> dSl
//   F = diag(Gamma) Q - (P T2) K       -> Fb
//   O_loc = P V_loc                    -> obuf (O = O_loc + F S_c added later)
__global__ __launch_bounds__(512) void k_prepass(
    const float* __restrict__ q, const float* __restrict__ k,
    const float* __restrict__ v, const float* __restrict__ graw,
    const float* __restrict__ beta,
    float* __restrict__ Eb, float* __restrict__ Fb,
    float* __restrict__ dSl, float* __restrict__ obuf) {
  const int bx = blockIdx.x, c = bx >> 4, h = bx & 15, tid = threadIdx.x;
  const int t0 = c * 64;
  __shared__ float ks[64*65];
  __shared__ float AP[64*65];   // A, then P
  __shared__ float WQ[64*65];   // q staging, then W2, then R
  __shared__ float Xs[64*192];  // [beta*V (128) | diag / T2 (64)]
  __shared__ float bs[64], bts[64], es[64], gms[64];

  // phase 0: decay prefix + beta
  if (tid < 64) {
    float g = graw[(size_t)(t0 + tid)*16 + h];
    float b = g;
#pragma unroll
    for (int off = 1; off < 64; off <<= 1) {
      float p = __shfl_up(b, off, 64);
      if (tid >= off) b += p;
    }
    bs[tid] = b;
    bts[tid] = beta[(size_t)(t0 + tid)*16 + h];
  }
  __syncthreads();
  // phase 1: k load + es/gms
  for (int i = tid; i < 4096; i += 512) {
    int t = i >> 6, dk = i & 63;
    ks[t*65 + dk] = k[(size_t)(t0 + t)*1024 + h*64 + dk];
  }
  if (tid < 64) {
    es[tid]  = __expf(bs[63] - bs[tid]);
    gms[tid] = __expf(bs[tid]);
  }
  __syncthreads();
  // phase 2: X init + A build
  for (int i = tid; i < 8192; i += 512) {
    int t = i >> 7, dv = i & 127;
    Xs[t*192 + dv] = bts[t] * v[(size_t)(t0 + t)*2048 + h*128 + dv];
  }
  for (int p = tid; p < 4096; p += 512) {
    int t = p >> 6, s = p & 63;
    Xs[t*192 + 128 + s] = (s == t) ? bts[t]*gms[t] : 0.f;
    float a = 0.f;
    if (s < t) {
      float d0=0,d1=0,d2=0,d3=0;
      for (int dk = 0; dk < 64; dk += 4) {
        d0 += ks[t*65+dk  ]*ks[s*65+dk  ];
        d1 += ks[t*65+dk+1]*ks[s*65+dk+1];
        d2 += ks[t*65+dk+2]*ks[s*65+dk+2];
        d3 += ks[t*65+dk+3]*ks[s*65+dk+3];
      }
      a = bts[t] * __expf(bs[t]-bs[s]) * ((d0+d1)+(d2+d3));
    }
    AP[t*65+s] = a;
  }
  __syncthreads();
  // phase 3: forward substitution (192 independent columns, zero-padded tri)
  if (tid < 192) {
    for (int t = 1; t < 64; ++t) {
      float a0=0,a1=0,a2=0,a3=0;
      int send = (t + 3) & ~3;
      for (int s = 0; s < send; s += 4) {
        a0 += AP[t*65+s  ]*Xs[(s  )*192+tid];
        a1 += AP[t*65+s+1]*Xs[(s+1)*192+tid];
        a2 += AP[t*65+s+2]*Xs[(s+2)*192+tid];
        a3 += AP[t*65+s+3]*Xs[(s+3)*192+tid];
      }
      Xs[t*192+tid] -= ((a0+a1)+(a2+a3));
    }
  }
  __syncthreads();
  // phase 4: stage q into WQ, then build P into AP
  for (int i = tid; i < 4096; i += 512) {
    int t = i >> 6, dk = i & 63;
    WQ[t*65 + dk] = q[(size_t)(t0 + t)*1024 + h*64 + dk];
  }
  __syncthreads();
  for (int p = tid; p < 4096; p += 512) {
    int t = p >> 6, s = p & 63;
    float a = 0.f;
    if (s <= t) {
      float d0=0,d1=0,d2=0,d3=0;
      for (int dk = 0; dk < 64; dk += 4) {
        d0 += WQ[t*65+dk  ]*ks[s*65+dk  ];
        d1 += WQ[t*65+dk+1]*ks[s*65+dk+1];
        d2 += WQ[t*65+dk+2]*ks[s*65+dk+2];
        d3 += WQ[t*65+dk+3]*ks[s*65+dk+3];
      }
      a = __expf(bs[t]-bs[s]) * ((d0+d1)+(d2+d3));
    }
    AP[t*65+s] = a;
  }
  __syncthreads();
  // phase 5: W2 = Kbar^T T2 (into WQ); dS_loc; O_loc
  {
    int j = tid & 63, ig = tid >> 6;
#pragma unroll
    for (int ib = 0; ib < 2; ++ib) {
      int i0 = ig*8 + ib*4;
      float a0=0,a1=0,a2=0,a3=0;
      for (int s = 0; s < 64; ++s) {
        float bx2 = es[s] * Xs[s*192 + 128 + j];
        a0 += ks[s*65+i0  ]*bx2;
        a1 += ks[s*65+i0+1]*bx2;
        a2 += ks[s*65+i0+2]*bx2;
        a3 += ks[s*65+i0+3]*bx2;
      }
      WQ[(i0  )*65+j] = a0;
      WQ[(i0+1)*65+j] = a1;
      WQ[(i0+2)*65+j] = a2;
      WQ[(i0+3)*65+j] = a3;
    }
  }
  {
    int j = tid & 127, ig = tid >> 7;
    size_t db = (size_t)bx * 8192;
#pragma unroll
    for (int ib = 0; ib < 4; ++ib) {
      int i0 = ig*16 + ib*4;
      float a0=0,a1=0,a2=0,a3=0;
      for (int s = 0; s < 64; ++s) {
        float bx2 = es[s] * Xs[s*192 + j];
        a0 += ks[s*65+i0  ]*bx2;
        a1 += ks[s*65+i0+1]*bx2;
        a2 += ks[s*65+i0+2]*bx2;
        a3 += ks[s*65+i0+3]*bx2;
      }
      dSl[db + (size_t)(i0  )*128 + j] = a0;
      dSl[db + (size_t)(i0+1)*128 + j] = a1;
      dSl[db + (size_t)(i0+2)*128 + j] = a2;
      dSl[db + (size_t)(i0+3)*128 + j] = a3;
    }
#pragma unroll
    for (int ib = 0; ib < 4; ++ib) {
      int i0 = ig*16 + ib*4;
      float a0=0,a1=0,a2=0,a3=0;
      for (int s = 0; s < 64; ++s) {
        float bx2 = Xs[s*192 + j];
        a0 += AP[(i0  )*65+s]*bx2;
        a1 += AP[(i0+1)*65+s]*bx2;
        a2 += AP[(i0+2)*65+s]*bx2;
        a3 += AP[(i0+3)*65+s]*bx2;
      }
      obuf[(size_t)(t0+i0  )*2048 + h*128 + j] = a0;
      obuf[(size_t)(t0+i0+1)*2048 + h*128 + j] = a1;
      obuf[(size_t)(t0+i0+2)*2048 + h*128 + j] = a2;
      obuf[(size_t)(t0+i0+3)*2048 + h*128 + j] = a3;
    }
  }
  __syncthreads();
  // phase 6: E = Gamma_C I - W2 @ K -> Eb
  {
    int j = tid & 63, ig = tid >> 6;
    float gC = gms[63];
    size_t eb = (size_t)bx * 4096;
#pragma unroll
    for (int ib = 0; ib < 2; ++ib) {
      int i0 = ig*8 + ib*4;
      float a0=0,a1=0,a2=0,a3=0;
      for (int s = 0; s < 64; ++s) {
        float bx2 = ks[s*65 + j];
        a0 += WQ[(i0  )*65+s]*bx2;
        a1 += WQ[(i0+1)*65+s]*bx2;
        a2 += WQ[(i0+2)*65+s]*bx2;
        a3 += WQ[(i0+3)*65+s]*bx2;
      }
      Eb[eb + (i0  )*64 + j] = ((i0  )==j ? gC : 0.f) - a0;
      Eb[eb + (i0+1)*64 + j] = ((i0+1)==j ? gC : 0.f) - a1;
      Eb[eb + (i0+2)*64 + j] = ((i0+2)==j ? gC : 0.f) - a2;
      Eb[eb + (i0+3)*64 + j] = ((i0+3)==j ? gC : 0.f) - a3;
    }
  }
  __syncthreads();
  // phase 7: R = P @ T2 (into WQ)
  {
    int j = tid & 63, ig = tid >> 6;
#pragma unroll
    for (int ib = 0; ib < 2; ++ib) {
      int i0 = ig*8 + ib*4;
      float a0=0,a1=0,a2=0,a3=0;
      for (int s = 0; s < 64; ++s) {
        float bx2 = Xs[s*192 + 128 + j];
        a0 += AP[(i0  )*65+s]*bx2;
        a1 += AP[(i0+1)*65+s]*bx2;
        a2 += AP[(i0+2)*65+s]*bx2;
        a3 += AP[(i0+3)*65+s]*bx2;
      }
      WQ[(i0  )*65+j] = a0;
      WQ[(i0+1)*65+j] = a1;
      WQ[(i0+2)*65+j] = a2;
      WQ[(i0+3)*65+j] = a3;
    }
  }
  __syncthreads();
  // phase 8: F = diag(Gamma) Q - R @ K -> Fb   (q re-read from global)
  {
    int j = tid & 63, ig = tid >> 6;
    size_t fb = (size_t)bx * 4096;
#pragma unroll
    for (int ib = 0; ib < 2; ++ib) {
      int i0 = ig*8 + ib*4;
      float a0=0,a1=0,a2=0,a3=0;
      for (int s = 0; s < 64; ++s) {
        float bx2 = ks[s*65 + j];
        a0 += WQ[(i0  )*65+s]*bx2;
        a1 += WQ[(i0+1)*65+s]*bx2;
        a2 += WQ[(i0+2)*65+s]*bx2;
        a3 += WQ[(i0+3)*65+s]*bx2;
      }
      Fb[fb + (i0  )*64 + j] = gms[i0  ]*q[(size_t)(t0+i0  )*1024 + h*64 + j] - a0;
      Fb[fb + (i0+1)*64 + j] = gms[i0+1]*q[(size_t)(t0+i0+1)*1024 + h*64 + j] - a1;
      Fb[fb + (i0+2)*64 + j] = gms[i0+2]*q[(size_t)(t0+i0+2)*1024 + h*64 + j] - a2;
      Fb[fb + (i0+3)*64 + j] = gms[i0+3]*q[(size_t)(t0+i0+3)*1024 + h*64 + j] - a3;
    }
  }
}

// ---------------- sequential chunk recurrence: S_{c+1} = E_c S_c + dS_c ----------------
// grid 128 = 16 heads x 8 dv-groups(16 wide), 256 threads.
__global__ __launch_bounds__(256) void k_seq(const float* __restrict__ Eb,
    const float* __restrict__ dSl, float* __restrict__ Sc) {
  const int h = blockIdx.x >> 3, dvg = blockIdx.x & 7;
  const int tid = threadIdx.x;
  __shared__ float Es[64*65];
  __shared__ float Sbuf[2][64*16];
  const int j = tid & 15, dkg = tid >> 4;
  const int dk0 = dkg*4;
  for (int i = tid; i < 1024; i += 256) Sbuf[0][i] = 0.f;
  __syncthreads();
  int cur = 0;
  for (int cc = 0; cc < 32; ++cc) {
    int ch = cc*16 + h;
    // store S_c (state at chunk start)
    for (int i = tid; i < 1024; i += 256) {
      int dk = i >> 4, jj = i & 15;
      Sc[(size_t)ch*8192 + dk*128 + dvg*16 + jj] = Sbuf[cur][dk*16 + jj];
    }
    // load E_c
    for (int i = tid; i < 4096; i += 256) {
      int dk = i >> 6, t = i & 63;
      Es[dk*65 + t] = Eb[(size_t)ch*4096 + i];
    }
    __syncthreads();
    size_t db = (size_t)ch*8192 + dvg*16 + j;
    float a0 = dSl[db + (size_t)(dk0  )*128];
    float a1 = dSl[db + (size_t)(dk0+1)*128];
    float a2 = dSl[db + (size_t)(dk0+2)*128];
    float a3 = dSl[db + (size_t)(dk0+3)*128];
    for (int t = 0; t < 64; ++t) {
      float sv = Sbuf[cur][t*16 + j];
      a0 += Es[(dk0  )*65+t]*sv;
      a1 += Es[(dk0+1)*65+t]*sv;
      a2 += Es[(dk0+2)*65+t]*sv;
      a3 += Es[(dk0+3)*65+t]*sv;
    }
    Sbuf[cur^1][(dk0  )*16+j] = a0;
    Sbuf[cur^1][(dk0+1)*16+j] = a1;
    Sbuf[cur^1][(dk0+2)*16+j] = a2;
    Sbuf[cur^1][(dk0+3)*16+j] = a3;
    cur ^= 1;
    __syncthreads();
  }
}

// ---------------- parallel output pass: O_c += F_c S_c ----------------
__global__ __launch_bounds__(256) void k_opass(const float* __restrict__ Fb,
    const float* __restrict__ Sc, float* __restrict__ obuf) {
  const int bx = blockIdx.x, c = bx >> 4, h = bx & 15;
  const int tid = threadIdx.x;
  __shared__ float Fs[64*65];
  __shared__ float Ss[64*128];
  for (int i = tid; i < 4096; i += 256) {
    int t = i >> 6, dk = i & 63;
    Fs[t*65 + dk] = Fb[(size_t)bx*4096 + i];
  }
  for (int i = tid; i < 8192; i += 256) Ss[i] = Sc[(size_t)bx*8192 + i];
  __syncthreads();
  const int j = tid & 127, ig = tid >> 7;
#pragma unroll
  for (int ib = 0; ib < 8; ++ib) {
    int i0 = ig*32 + ib*4;
    float a0=0,a1=0,a2=0,a3=0;
    for (int s = 0; s < 64; ++s) {
      float bx2 = Ss[s*128 + j];
      a0 += Fs[(i0  )*65+s]*bx2;
      a1 += Fs[(i0+1)*65+s]*bx2;
      a2 += Fs[(i0+2)*65+s]*bx2;
      a3 += Fs[(i0+3)*65+s]*bx2;
    }
    size_t base = (size_t)(c*64)*2048 + h*128 + j;
    obuf[base + (size_t)(i0  )*2048] += a0;
    obuf[base + (size_t)(i0+1)*2048] += a1;
    obuf[base + (size_t)(i0+2)*2048] += a2;
    obuf[base + (size_t)(i0+3)*2048] += a3;
  }
}

// ---------------- gated RMSNorm on o, write bf16 ----------------
__global__ __launch_bounds__(64) void k_gatenorm(const float* __restrict__ o,
    const float* __restrict__ gpre, const float* __restrict__ onw,
    bf16* __restrict__ og) {
  int t = blockIdx.x, hh = blockIdx.y, lane = threadIdx.x;
  const float* obase = o + (size_t)t*2048 + hh*128;
  float2 o2 = *(const float2*)(obase + lane*2);
  float ss = wredsum(o2.x*o2.x + o2.y*o2.y);
  float rs = rsqrtf(ss * (1.f/128.f) + 1e-5f);
  float2 nw = *(const float2*)(onw + lane*2);
  float2 g2 = *(const float2*)(gpre + (size_t)t*2048 + hh*128 + lane*2);
  float r0 = o2.x * rs * nw.x * (g2.x * sigmoidf_(g2.x));
  float r1 = o2.y * rs * nw.y * (g2.y * sigmoidf_(g2.y));
  bf16x2v b; b[0] = (bf16)r0; b[1] = (bf16)r1;
  *(bf16x2v*)(og + (size_t)t*2048 + hh*128 + lane*2) = b;
}

extern "C" void kernel_launch(void* const* d_in, const int* in_sizes, int n_in,
                              void* d_out, int out_size, void* d_ws, size_t ws_size,
                              hipStream_t stream) {
  const float* hs   = (const float*)d_in[0];
  const float* nw   = (const float*)d_in[1];
  const float* qw   = (const float*)d_in[2];
  const float* kw   = (const float*)d_in[3];
  const float* vw   = (const float*)d_in[4];
  const float* aw   = (const float*)d_in[5];
  const float* bw   = (const float*)d_in[6];
  const float* gw   = (const float*)d_in[7];
  const float* dtb  = (const float*)d_in[8];
  const float* alog = (const float*)d_in[9];
  const float* cqw  = (const float*)d_in[10];
  const float* ckw  = (const float*)d_in[11];
  const float* cvw  = (const float*)d_in[12];
  const float* onw  = (const float*)d_in[13];
  const float* opw  = (const float*)d_in[14];
  const float* ow   = (const float*)d_in[15];
  float* out = (float*)d_out;

  char* p = (char*)d_ws;
  auto alloc = [&](size_t bytes) { char* r = p; p += (bytes + 255) & ~255ull; return r; };
  float* xf    = (float*)alloc((size_t)2048*1024*4);
  bf16*  xb    = (bf16*) alloc((size_t)2048*1024*2);
  bf16*  qwb   = (bf16*) alloc((size_t)1024*1024*2);
  bf16*  kwb   = (bf16*) alloc((size_t)1024*1024*2);
  bf16*  vwb   = (bf16*) alloc((size_t)2048*1024*2);
  bf16*  gwb   = (bf16*) alloc((size_t)2048*1024*2);
  bf16*  opwb  = (bf16*) alloc((size_t)1024*2048*2);
  bf16*  owb   = (bf16*) alloc((size_t)1024*1024*2);
  float* qpre  = (float*)alloc((size_t)2048*1024*4);
  float* kpre  = (float*)alloc((size_t)2048*1024*4);
  float* vpre  = (float*)alloc((size_t)2048*2048*4);
  float* gpre  = (float*)alloc((size_t)2048*2048*4);
  float* qpost = (float*)alloc((size_t)2048*1024*4);   // Sc aliases qpost+kpost later
  float* kpost = (float*)alloc((size_t)2048*1024*4);
  float* vpost = (float*)alloc((size_t)2048*2048*4);
  float* graw  = (float*)alloc((size_t)2048*16*4);
  float* btb   = (float*)alloc((size_t)2048*16*4);
  float* ob    = (float*)alloc((size_t)2048*2048*4);
  bf16*  ogb   = (bf16*) alloc((size_t)2048*2048*2);
  bf16*  h1b   = (bf16*) alloc((size_t)2048*1024*2);

  // aliases for chunked-scan buffers (re-use dead fp32 intermediates):
  float* Eb  = qpre;           // 512*4096*4 = 8 MB  (qpre dead after k_convqk)
  float* Fb  = kpre;           // 512*4096*4 = 8 MB  (kpre dead after k_convqk)
  float* dSl = vpre;           // 512*8192*4 = 16 MB (vpre dead after k_convv)
  float* Sc  = qpost;          // 512*8192*4 = 16 MB spans qpost+kpost (dead after k_prepass)

  k_rmsnorm<<<2048, 256, 0, stream>>>(hs, nw, xf, xb);
  k_castw<<<4608, 256, 0, stream>>>(qw, kw, vw, gw, opw, ow, qwb, kwb, vwb, gwb, opwb, owb);
  k_gemm_proj<<<dim3(16,16,4), 256, 0, stream>>>(xb, qwb, kwb, vwb, gwb, qpre, kpre, vpre, gpre);
  k_ab<<<2048, 64, 0, stream>>>(xf, aw, bw, dtb, alog, graw, btb);
  k_convqk<<<dim3(2048,4,2), 256, 0, stream>>>(qpre, kpre, cqw, ckw, qpost, kpost);
  k_convv<<<dim3(2048,2,1), 256, 0, stream>>>(vpre, cvw, vpost);
  k_prepass<<<512, 512, 0, stream>>>(qpost, kpost, vpost, graw, btb, Eb, Fb, dSl, ob);
  k_seq<<<128, 256, 0, stream>>>(Eb, dSl, Sc);
  k_opass<<<512, 256, 0, stream>>>(Fb, Sc, ob);
  k_gatenorm<<<dim3(2048,16,1), 64, 0, stream>>>(ob, gpre, onw, ogb);
  k_gemm_bt<bf16><<<dim3(8,16,1), 256, 0, stream>>>(ogb, opwb, h1b, 1024, 2048);
  k_gemm_bt<float><<<dim3(8,16,1), 256, 0, stream>>>(h1b, owb, out, 1024, 1024);
}

// Round 3
// 552.165 us; speedup vs baseline: 2.0536x; 1.6277x over previous
//
#include <hip/hip_runtime.h>
#include <math.h>

#define TT 2048

typedef __bf16 bf16;
typedef __bf16 bf16x8 __attribute__((ext_vector_type(8)));
typedef __bf16 bf16x4v __attribute__((ext_vector_type(4)));
typedef __bf16 bf16x2v __attribute__((ext_vector_type(2)));
typedef float f32x4 __attribute__((ext_vector_type(4)));

__device__ __forceinline__ float wredsum(float v) {
#pragma unroll
  for (int off = 32; off > 0; off >>= 1) v += __shfl_xor(v, off, 64);
  return v;
}
__device__ __forceinline__ float sigmoidf_(float x) { return 1.f / (1.f + __expf(-x)); }

// ---------------- RMSNorm: h[2048,1024] -> xf (f32), xb (bf16) ----------------
__global__ __launch_bounds__(256) void k_rmsnorm(const float* __restrict__ h,
    const float* __restrict__ nw, float* __restrict__ xf, bf16* __restrict__ xb) {
  int t = blockIdx.x, tid = threadIdx.x;
  float4 hv = *(const float4*)(h + (size_t)t*1024 + tid*4);
  float ss = hv.x*hv.x + hv.y*hv.y + hv.z*hv.z + hv.w*hv.w;
  __shared__ float red[4];
  float wsum = wredsum(ss);
  if ((tid & 63) == 0) red[tid >> 6] = wsum;
  __syncthreads();
  float tot = red[0] + red[1] + red[2] + red[3];
  float rs = rsqrtf(tot * (1.f/1024.f) + 1e-6f);
  float4 w4 = *(const float4*)(nw + tid*4);
  float4 y;
  y.x = hv.x*rs*w4.x; y.y = hv.y*rs*w4.y; y.z = hv.z*rs*w4.z; y.w = hv.w*rs*w4.w;
  *(float4*)(xf + (size_t)t*1024 + tid*4) = y;
  bf16x4v b; b[0]=(bf16)y.x; b[1]=(bf16)y.y; b[2]=(bf16)y.z; b[3]=(bf16)y.w;
  *(bf16x4v*)(xb + (size_t)t*1024 + tid*4) = b;
}

// ---------------- cast weights f32 -> bf16 (6 tensors) ----------------
__global__ void k_castw(const float* __restrict__ qw, const float* __restrict__ kw,
    const float* __restrict__ vw, const float* __restrict__ gw,
    const float* __restrict__ opw, const float* __restrict__ ow,
    bf16* qwb, bf16* kwb, bf16* vwb, bf16* gwb, bf16* opwb, bf16* owb) {
  for (long u = (long)blockIdx.x*256 + threadIdx.x; u < 2359296; u += (long)gridDim.x*256) {
    const float* src; bf16* dst; long l;
    if      (u <  262144) { src=qw;  dst=qwb;  l=u; }
    else if (u <  524288) { src=kw;  dst=kwb;  l=u-262144; }
    else if (u < 1048576) { src=vw;  dst=vwb;  l=u-524288; }
    else if (u < 1572864) { src=gw;  dst=gwb;  l=u-1048576; }
    else if (u < 2097152) { src=opw; dst=opwb; l=u-1572864; }
    else                  { src=ow;  dst=owb;  l=u-2097152; }
    float4 s = *(const float4*)(src + l*4);
    bf16x4v b; b[0]=(bf16)s.x; b[1]=(bf16)s.y; b[2]=(bf16)s.z; b[3]=(bf16)s.w;
    *(bf16x4v*)(dst + l*4) = b;
  }
}

// ---------------- bf16 MFMA GEMM: C[M,N] = A[M,K] * B[N,K]^T ----------------
template <typename OutT>
__device__ __forceinline__ void gemm_body(const bf16* __restrict__ A,
    const bf16* __restrict__ B, OutT* __restrict__ C, int N, int K, int m0, int n0) {
  __shared__ bf16 As[128*32];
  __shared__ bf16 Bs[128*32];
  const int tid = threadIdx.x, lane = tid & 63, wave = tid >> 6;
  const int wm = (wave >> 1) * 64, wn = (wave & 1) * 64;
  const int srow = wave*16 + (lane >> 2);
  const int skk = (lane & 3) * 8;
  const int quad = lane >> 4, l16 = lane & 15;
  f32x4 acc[4][4] = {};
  for (int k0 = 0; k0 < K; k0 += 32) {
    __syncthreads();
#pragma unroll
    for (int i = 0; i < 2; ++i) {
      int r = i*64 + srow;
      __builtin_amdgcn_global_load_lds(
        (__attribute__((address_space(1))) void*)(A + (size_t)(m0 + r)*K + k0 + skk),
        (__attribute__((address_space(3))) void*)(As + r*32 + skk), 16, 0, 0);
      __builtin_amdgcn_global_load_lds(
        (__attribute__((address_space(1))) void*)(B + (size_t)(n0 + r)*K + k0 + skk),
        (__attribute__((address_space(3))) void*)(Bs + r*32 + skk), 16, 0, 0);
    }
    __syncthreads();
    bf16x8 af[4], bfr[4];
#pragma unroll
    for (int mt = 0; mt < 4; ++mt)
      af[mt] = *(const bf16x8*)(As + (wm + mt*16 + l16)*32 + quad*8);
#pragma unroll
    for (int nt = 0; nt < 4; ++nt)
      bfr[nt] = *(const bf16x8*)(Bs + (wn + nt*16 + l16)*32 + quad*8);
#pragma unroll
    for (int mt = 0; mt < 4; ++mt)
#pragma unroll
      for (int nt = 0; nt < 4; ++nt)
        acc[mt][nt] = __builtin_amdgcn_mfma_f32_16x16x32_bf16(af[mt], bfr[nt], acc[mt][nt], 0, 0, 0);
  }
#pragma unroll
  for (int mt = 0; mt < 4; ++mt)
#pragma unroll
    for (int nt = 0; nt < 4; ++nt)
#pragma unroll
      for (int r = 0; r < 4; ++r) {
        int row = m0 + wm + mt*16 + quad*4 + r;
        int col = n0 + wn + nt*16 + l16;
        C[(size_t)row*N + col] = (OutT)acc[mt][nt][r];
      }
}

__global__ __launch_bounds__(256) void k_gemm_proj(const bf16* __restrict__ A,
    const bf16* __restrict__ qwb, const bf16* __restrict__ kwb,
    const bf16* __restrict__ vwb, const bf16* __restrict__ gwb,
    float* __restrict__ qpre, float* __restrict__ kpre,
    float* __restrict__ vpre, float* __restrict__ gpre) {
  int z = blockIdx.z;
  const bf16* B; float* C; int N;
  if      (z == 0) { B = qwb; C = qpre; N = 1024; }
  else if (z == 1) { B = kwb; C = kpre; N = 1024; }
  else if (z == 2) { B = vwb; C = vpre; N = 2048; }
  else             { B = gwb; C = gpre; N = 2048; }
  if ((int)blockIdx.x * 128 >= N) return;
  gemm_body<float>(A, B, C, N, 1024, blockIdx.y*128, blockIdx.x*128);
}

template <typename OutT>
__global__ __launch_bounds__(256) void k_gemm_bt(const bf16* __restrict__ A,
    const bf16* __restrict__ B, OutT* __restrict__ C, int N, int K) {
  gemm_body<OutT>(A, B, C, N, K, blockIdx.y*128, blockIdx.x*128);
}

// ---------------- a/b projections (fp32) -> g (log decay), beta ----------------
__global__ __launch_bounds__(64) void k_ab(const float* __restrict__ xf,
    const float* __restrict__ aw, const float* __restrict__ bw,
    const float* __restrict__ dtb, const float* __restrict__ alog,
    float* __restrict__ graw, float* __restrict__ beta) {
  int t = blockIdx.x, lane = threadIdx.x;
  __shared__ __align__(16) float xs[1024];
#pragma unroll
  for (int i = 0; i < 16; ++i) xs[i*64 + lane] = xf[(size_t)t*1024 + i*64 + lane];
  __syncthreads();
  const float4* x4 = (const float4*)xs;
  for (int hh = 0; hh < 16; ++hh) {
    float sa = 0.f, sb = 0.f;
#pragma unroll
    for (int i = 0; i < 4; ++i) {
      float4 xv = x4[i*64 + lane];
      float4 av = *(const float4*)(aw + hh*1024 + i*256 + lane*4);
      float4 bv = *(const float4*)(bw + hh*1024 + i*256 + lane*4);
      sa += xv.x*av.x + xv.y*av.y + xv.z*av.z + xv.w*av.w;
      sb += xv.x*bv.x + xv.y*bv.y + xv.z*bv.z + xv.w*bv.w;
    }
    sa = wredsum(sa); sb = wredsum(sb);
    if (lane == 0) {
      float ap = sa + dtb[hh];
      float sp = (ap > 20.f) ? ap : log1pf(expf(ap));
      graw[t*16 + hh] = -expf(alog[hh]) * sp;
      beta[t*16 + hh] = 1.f / (1.f + expf(-sb));
    }
  }
}

// ---------------- conv(K=4)+silu for q,k + per-head postprocessing ----------------
__global__ __launch_bounds__(256) void k_convqk(const float* __restrict__ qpre,
    const float* __restrict__ kpre, const float* __restrict__ cqw,
    const float* __restrict__ ckw, float* __restrict__ qpost, float* __restrict__ kpost) {
  int t = blockIdx.x, cb = blockIdx.y, isk = blockIdx.z;
  int c = cb*256 + threadIdx.x;
  const float* in = isk ? kpre : qpre;
  const float* w  = isk ? ckw : cqw;
  float4 wv = *(const float4*)(w + c*4);
  float y = 0.f;
  int tt = t - 3;
  if (tt     >= 0) y += in[(size_t)(tt  )*1024 + c] * wv.x;
  if (tt + 1 >= 0) y += in[(size_t)(tt+1)*1024 + c] * wv.y;
  if (tt + 2 >= 0) y += in[(size_t)(tt+2)*1024 + c] * wv.z;
  y += in[(size_t)t*1024 + c] * wv.w;
  y = y * sigmoidf_(y);
  if (isk) {
    float m = wredsum(y) * (1.f/64.f);
    y -= m;
    float ss = wredsum(y*y);
    y *= rsqrtf(ss + 1e-6f);
    kpost[(size_t)t*1024 + c] = y;
  } else {
    float ss = wredsum(y*y);
    y *= rsqrtf(ss + 1e-6f) * 0.125f;
    qpost[(size_t)t*1024 + c] = y;
  }
}

// ---------------- conv(K=4)+silu for v ----------------
__global__ __launch_bounds__(256) void k_convv(const float* __restrict__ vpre,
    const float* __restrict__ cvw, float* __restrict__ vpost) {
  int t = blockIdx.x;
  int c0 = blockIdx.y*1024 + threadIdx.x*4;
  float a0=0.f, a1=0.f, a2=0.f, a3=0.f;
#pragma unroll
  for (int i = 0; i < 4; ++i) {
    int tt = t - 3 + i;
    if (tt < 0) continue;
    float4 in4 = *(const float4*)(vpre + (size_t)tt*2048 + c0);
    a0 += in4.x * cvw[(c0+0)*4 + i];
    a1 += in4.y * cvw[(c0+1)*4 + i];
    a2 += in4.z * cvw[(c0+2)*4 + i];
    a3 += in4.w * cvw[(c0+3)*4 + i];
  }
  float4 o4;
  o4.x = a0 * sigmoidf_(a0); o4.y = a1 * sigmoidf_(a1);
  o4.z = a2 * sigmoidf_(a2); o4.w = a3 * sigmoidf_(a3);
  *(float4*)(vpost + (size_t)t*2048 + c0) = o4;
}

// ---------------- MFMA chunked delta-rule pre-pass ----------------
// grid 512 = 32 chunks x 16 heads, 512 threads (8 waves: 4 row-bands x 2 col-halves).
// All matmuls bf16 MFMA (fp32 accumulate). (I+A)^-1 via nilpotent squaring:
// N = -A strictly lower => (I+A)^-1 = (I+N)(I+N^2)(I+N^4)(I+N^8)(I+N^16)(I+N^32).
// LDS stride 72 (144B rows) keeps ds_read_b128 at 2-way bank aliasing (free).
#define S72 72

template<int NT>
__device__ __forceinline__ void mm_band(const bf16* A_lds, const bf16* B_lds,
    int w16, int cb, int l16, int quad, f32x4* acc) {
#pragma unroll
  for (int n = 0; n < NT; ++n) { acc[n][0]=0.f; acc[n][1]=0.f; acc[n][2]=0.f; acc[n][3]=0.f; }
#pragma unroll
  for (int kt = 0; kt < 2; ++kt) {
    bf16x8 af = *(const bf16x8*)(A_lds + (w16 + l16)*S72 + kt*32 + quad*8);
#pragma unroll
    for (int n = 0; n < NT; ++n) {
      bf16x8 bf = *(const bf16x8*)(B_lds + (cb + n*16 + l16)*S72 + kt*32 + quad*8);
      acc[n] = __builtin_amdgcn_mfma_f32_16x16x32_bf16(af, bf, acc[n], 0, 0, 0);
    }
  }
}

__device__ __forceinline__ bf16x8 ldg_frag(const float* p) {
  float4 a = *(const float4*)p;
  float4 b = *(const float4*)(p + 4);
  bf16x8 r;
  r[0]=(bf16)a.x; r[1]=(bf16)a.y; r[2]=(bf16)a.z; r[3]=(bf16)a.w;
  r[4]=(bf16)b.x; r[5]=(bf16)b.y; r[6]=(bf16)b.z; r[7]=(bf16)b.w;
  return r;
}

__global__ __launch_bounds__(512) void k_prepass(
    const float* __restrict__ q, const float* __restrict__ k,
    const float* __restrict__ v, const float* __restrict__ graw,
    const float* __restrict__ beta,
    float* __restrict__ Eb, float* __restrict__ Fb,
    float* __restrict__ dSl, float* __restrict__ obuf) {
  const int bx = blockIdx.x, c = bx >> 4, h = bx & 15, tid = threadIdx.x;
  const int t0 = c * 64;
  const int wave = tid >> 6, lane = tid & 63, l16 = lane & 15, quad = lane >> 4;
  const int w16 = (wave >> 1) * 16;   // row band
  const int chh = wave & 1;           // column half

  __shared__ bf16 SM[50688];          // 101376 B
  __shared__ float bs[64], bts_s[64], es[64], gms[64];
  bf16* Kr    = SM;                   // K row-major [t][i]
  bf16* KT    = SM + 4608;            // K^T [i][t]
  bf16* KbT   = SM + 9216;            // es[t]*K[t][i] at [i][t]
  bf16* Pm    = SM + 13824;           // P row-major [t][s]
  bf16* powR0 = SM + 18432;
  bf16* powT0 = SM + 23040;
  bf16* powR1 = SM + 27648;
  bf16* powT1 = SM + 32256;
  bf16* prod0 = SM + 36864;
  bf16* prod1 = SM + 41472;
  bf16* T2T   = SM + 46080;           // [j][s] = beta_j*gamma_j*M[s][j]
  bf16* VT    = SM + 18432;           // alias pow0 region: [j][t] = beta_t*v[t][j]
  bf16* VlT   = SM + 27648;           // alias pow1 region: V_loc^T [j][t]

  // phase 0: decay prefix + beta (wave 0)
  if (tid < 64) {
    float g = graw[(size_t)(t0 + tid)*16 + h];
    float b = g;
#pragma unroll
    for (int off = 1; off < 64; off <<= 1) {
      float p = __shfl_up(b, off, 64);
      if (tid >= off) b += p;
    }
    bs[tid] = b;
    bts_s[tid] = beta[(size_t)(t0 + tid)*16 + h];
    float b63 = __shfl(b, 63, 64);
    es[tid] = __expf(b63 - b);
    gms[tid] = __expf(b);
  }
  __syncthreads();

  // K load: build Kr, KT, KbT
  for (int idx = tid; idx < 4096; idx += 512) {
    int t = idx >> 6, i = idx & 63;
    float kv = k[(size_t)(t0 + t)*1024 + h*64 + i];
    bf16 kb = (bf16)kv;
    Kr[t*S72 + i] = kb;
    KT[i*S72 + t] = kb;
    KbT[i*S72 + t] = (bf16)(kv * es[t]);
  }
  __syncthreads();

  // A-build: N = -A from K K^T; also prod0 = I + N
  {
    f32x4 acc[2];
    mm_band<2>(Kr, Kr, w16, chh*32, l16, quad, acc);
#pragma unroll
    for (int n = 0; n < 2; ++n) {
      int col = chh*32 + n*16 + l16;
      bf16x4v tv;
#pragma unroll
      for (int r = 0; r < 4; ++r) {
        int row = w16 + quad*4 + r;
        float nv = 0.f;
        if (row > col) nv = -bts_s[row] * __expf(bs[row] - bs[col]) * acc[n][r];
        bf16 nb = (bf16)nv;
        powR0[row*S72 + col] = nb;
        tv[r] = nb;
        prod0[row*S72 + col] = (row == col) ? (bf16)1.f : nb;
      }
      *(bf16x4v*)(powT0 + col*S72 + w16 + quad*4) = tv;
    }
  }
  // P-build: P[t][s] = exp(b_t-b_s) q_t.k_s (s<=t), q fragments from global
  {
    f32x4 acc[2];
#pragma unroll
    for (int n = 0; n < 2; ++n) { acc[n][0]=0.f; acc[n][1]=0.f; acc[n][2]=0.f; acc[n][3]=0.f; }
#pragma unroll
    for (int kt = 0; kt < 2; ++kt) {
      bf16x8 af = ldg_frag(q + (size_t)(t0 + w16 + l16)*1024 + h*64 + kt*32 + quad*8);
#pragma unroll
      for (int n = 0; n < 2; ++n) {
        bf16x8 bf = *(const bf16x8*)(Kr + (chh*32 + n*16 + l16)*S72 + kt*32 + quad*8);
        acc[n] = __builtin_amdgcn_mfma_f32_16x16x32_bf16(af, bf, acc[n], 0, 0, 0);
      }
    }
#pragma unroll
    for (int n = 0; n < 2; ++n) {
      int col = chh*32 + n*16 + l16;
#pragma unroll
      for (int r = 0; r < 4; ++r) {
        int row = w16 + quad*4 + r;
        float pv = (row >= col) ? __expf(bs[row] - bs[col]) * acc[n][r] : 0.f;
        Pm[row*S72 + col] = (bf16)pv;
      }
    }
  }
  __syncthreads();

  // squaring product chain
  int pc = 0, rc = 0;
#pragma unroll 1
  for (int i = 1; i <= 5; ++i) {
    bf16* sqA = pc ? powR1 : powR0;
    bf16* sqB = pc ? powT1 : powT0;
    bf16* sqRo = pc ? powR0 : powR1;
    bf16* sqTo = pc ? powT0 : powT1;
    {
      f32x4 acc[2];
      mm_band<2>(sqA, sqB, w16, chh*32, l16, quad, acc);
#pragma unroll
      for (int n = 0; n < 2; ++n) {
        int col = chh*32 + n*16 + l16;
        bf16x4v tv;
#pragma unroll
        for (int r = 0; r < 4; ++r) {
          int row = w16 + quad*4 + r;
          bf16 vb = (bf16)acc[n][r];
          sqRo[row*S72 + col] = vb;
          tv[r] = vb;
        }
        *(bf16x4v*)(sqTo + col*S72 + w16 + quad*4) = tv;
      }
    }
    __syncthreads();
    bf16* prA = rc ? prod1 : prod0;
    bf16* prO = rc ? prod0 : prod1;
    {
      f32x4 acc[2];
      mm_band<2>(prA, sqTo, w16, chh*32, l16, quad, acc);
#pragma unroll
      for (int n = 0; n < 2; ++n) {
        int col = chh*32 + n*16 + l16;
        bf16x4v tv;
#pragma unroll
        for (int r = 0; r < 4; ++r) {
          int row = w16 + quad*4 + r;
          float val = acc[n][r] + (float)prA[row*S72 + col];
          prO[row*S72 + col] = (bf16)val;
          tv[r] = (bf16)(val * bts_s[col] * gms[col]);
        }
        if (i == 5) *(bf16x4v*)(T2T + col*S72 + w16 + quad*4) = tv;
      }
    }
    __syncthreads();
    pc ^= 1; rc ^= 1;
  }
  bf16* Mrow = rc ? prod1 : prod0;   // rc = 1 after 5 iters -> prod1
  bf16* WR   = rc ? prod0 : prod1;

  // VT build (aliases pow0 region, now dead): VT[j][t] = beta_t * v[t][j]
  for (int idx = tid; idx < 8192; idx += 512) {
    int t = idx >> 7, j = idx & 127;
    VT[j*S72 + t] = (bf16)(bts_s[t] * v[(size_t)(t0 + t)*2048 + h*128 + j]);
  }
  __syncthreads();

  // V_loc = M (beta V): write V_loc^T
  {
    f32x4 acc[4];
    mm_band<4>(Mrow, VT, w16, chh*64, l16, quad, acc);
#pragma unroll
    for (int n = 0; n < 4; ++n) {
      int col = chh*64 + n*16 + l16;
      bf16x4v tv;
#pragma unroll
      for (int r = 0; r < 4; ++r) tv[r] = (bf16)acc[n][r];
      *(bf16x4v*)(VlT + col*S72 + w16 + quad*4) = tv;
    }
  }
  __syncthreads();

  // dS_loc = Kbar^T V_loc -> global
  {
    f32x4 acc[4];
    mm_band<4>(KbT, VlT, w16, chh*64, l16, quad, acc);
#pragma unroll
    for (int n = 0; n < 4; ++n) {
      int col = chh*64 + n*16 + l16;
#pragma unroll
      for (int r = 0; r < 4; ++r)
        dSl[(size_t)bx*8192 + (size_t)(w16 + quad*4 + r)*128 + col] = acc[n][r];
    }
  }
  // W2 = Kbar^T T2 -> WR (bf16 row-major)
  {
    f32x4 acc[2];
    mm_band<2>(KbT, T2T, w16, chh*32, l16, quad, acc);
#pragma unroll
    for (int n = 0; n < 2; ++n) {
      int col = chh*32 + n*16 + l16;
#pragma unroll
      for (int r = 0; r < 4; ++r)
        WR[(w16 + quad*4 + r)*S72 + col] = (bf16)acc[n][r];
    }
  }
  __syncthreads();
  // E = gamma_C I - W2 K -> global
  {
    f32x4 acc[2];
    mm_band<2>(WR, KT, w16, chh*32, l16, quad, acc);
    float gC = gms[63];
#pragma unroll
    for (int n = 0; n < 2; ++n) {
      int col = chh*32 + n*16 + l16;
#pragma unroll
      for (int r = 0; r < 4; ++r) {
        int row = w16 + quad*4 + r;
        Eb[(size_t)bx*4096 + row*64 + col] = ((row == col) ? gC : 0.f) - acc[n][r];
      }
    }
  }
  __syncthreads();   // E's reads of WR done before R overwrites
  // R = P T2 -> WR
  {
    f32x4 acc[2];
    mm_band<2>(Pm, T2T, w16, chh*32, l16, quad, acc);
#pragma unroll
    for (int n = 0; n < 2; ++n) {
      int col = chh*32 + n*16 + l16;
#pragma unroll
      for (int r = 0; r < 4; ++r)
        WR[(w16 + quad*4 + r)*S72 + col] = (bf16)acc[n][r];
    }
  }
  __syncthreads();
  // F = diag(gamma) Q - R K -> global
  {
    f32x4 acc[2];
    mm_band<2>(WR, KT, w16, chh*32, l16, quad, acc);
#pragma unroll
    for (int n = 0; n < 2; ++n) {
      int col = chh*32 + n*16 + l16;
#pragma unroll
      for (int r = 0; r < 4; ++r) {
        int row = w16 + quad*4 + r;
        float qv = q[(size_t)(t0 + row)*1024 + h*64 + col];
        Fb[(size_t)bx*4096 + row*64 + col] = gms[row]*qv - acc[n][r];
      }
    }
  }
  // O_loc = P V_loc -> global
  {
    f32x4 acc[4];
    mm_band<4>(Pm, VlT, w16, chh*64, l16, quad, acc);
#pragma unroll
    for (int n = 0; n < 4; ++n) {
      int col = chh*64 + n*16 + l16;
#pragma unroll
      for (int r = 0; r < 4; ++r)
        obuf[(size_t)(t0 + w16 + quad*4 + r)*2048 + h*128 + col] = acc[n][r];
    }
  }
}

// ---------------- sequential chunk recurrence: S_{c+1} = E_c S_c + dS_c ----------------
// grid 128 = 16 heads x 8 dv-groups(16 wide), 256 threads.
__global__ __launch_bounds__(256) void k_seq(const float* __restrict__ Eb,
    const float* __restrict__ dSl, float* __restrict__ Sc) {
  const int h = blockIdx.x >> 3, dvg = blockIdx.x & 7;
  const int tid = threadIdx.x;
  __shared__ float Es[64*65];
  __shared__ float Sbuf[2][64*16];
  const int j = tid & 15, dkg = tid >> 4;
  const int dk0 = dkg*4;
  for (int i = tid; i < 1024; i += 256) Sbuf[0][i] = 0.f;
  __syncthreads();
  int cur = 0;
  for (int cc = 0; cc < 32; ++cc) {
    int ch = cc*16 + h;
    for (int i = tid; i < 1024; i += 256) {
      int dk = i >> 4, jj = i & 15;
      Sc[(size_t)ch*8192 + dk*128 + dvg*16 + jj] = Sbuf[cur][dk*16 + jj];
    }
    for (int i = tid; i < 4096; i += 256) {
      int dk = i >> 6, t = i & 63;
      Es[dk*65 + t] = Eb[(size_t)ch*4096 + i];
    }
    __syncthreads();
    size_t db = (size_t)ch*8192 + dvg*16 + j;
    float a0 = dSl[db + (size_t)(dk0  )*128];
    float a1 = dSl[db + (size_t)(dk0+1)*128];
    float a2 = dSl[db + (size_t)(dk0+2)*128];
    float a3 = dSl[db + (size_t)(dk0+3)*128];
    for (int t = 0; t < 64; ++t) {
      float sv = Sbuf[cur][t*16 + j];
      a0 += Es[(dk0  )*65+t]*sv;
      a1 += Es[(dk0+1)*65+t]*sv;
      a2 += Es[(dk0+2)*65+t]*sv;
      a3 += Es[(dk0+3)*65+t]*sv;
    }
    Sbuf[cur^1][(dk0  )*16+j] = a0;
    Sbuf[cur^1][(dk0+1)*16+j] = a1;
    Sbuf[cur^1][(dk0+2)*16+j] = a2;
    Sbuf[cur^1][(dk0+3)*16+j] = a3;
    cur ^= 1;
    __syncthreads();
  }
}

// ---------------- parallel output pass: O_c += F_c S_c ----------------
__global__ __launch_bounds__(256) void k_opass(const float* __restrict__ Fb,
    const float* __restrict__ Sc, float* __restrict__ obuf) {
  const int bx = blockIdx.x, c = bx >> 4, h = bx & 15;
  const int tid = threadIdx.x;
  __shared__ float Fs[64*65];
  __shared__ float Ss[64*128];
  for (int i = tid; i < 4096; i += 256) {
    int t = i >> 6, dk = i & 63;
    Fs[t*65 + dk] = Fb[(size_t)bx*4096 + i];
  }
  for (int i = tid; i < 8192; i += 256) Ss[i] = Sc[(size_t)bx*8192 + i];
  __syncthreads();
  const int j = tid & 127, ig = tid >> 7;
#pragma unroll
  for (int ib = 0; ib < 8; ++ib) {
    int i0 = ig*32 + ib*4;
    float a0=0,a1=0,a2=0,a3=0;
    for (int s = 0; s < 64; ++s) {
      float bx2 = Ss[s*128 + j];
      a0 += Fs[(i0  )*65+s]*bx2;
      a1 += Fs[(i0+1)*65+s]*bx2;
      a2 += Fs[(i0+2)*65+s]*bx2;
      a3 += Fs[(i0+3)*65+s]*bx2;
    }
    size_t base = (size_t)(c*64)*2048 + h*128 + j;
    obuf[base + (size_t)(i0  )*2048] += a0;
    obuf[base + (size_t)(i0+1)*2048] += a1;
    obuf[base + (size_t)(i0+2)*2048] += a2;
    obuf[base + (size_t)(i0+3)*2048] += a3;
  }
}

// ---------------- gated RMSNorm on o, write bf16 ----------------
__global__ __launch_bounds__(64) void k_gatenorm(const float* __restrict__ o,
    const float* __restrict__ gpre, const float* __restrict__ onw,
    bf16* __restrict__ og) {
  int t = blockIdx.x, hh = blockIdx.y, lane = threadIdx.x;
  const float* obase = o + (size_t)t*2048 + hh*128;
  float2 o2 = *(const float2*)(obase + lane*2);
  float ss = wredsum(o2.x*o2.x + o2.y*o2.y);
  float rs = rsqrtf(ss * (1.f/128.f) + 1e-5f);
  float2 nw = *(const float2*)(onw + lane*2);
  float2 g2 = *(const float2*)(gpre + (size_t)t*2048 + hh*128 + lane*2);
  float r0 = o2.x * rs * nw.x * (g2.x * sigmoidf_(g2.x));
  float r1 = o2.y * rs * nw.y * (g2.y * sigmoidf_(g2.y));
  bf16x2v b; b[0] = (bf16)r0; b[1] = (bf16)r1;
  *(bf16x2v*)(og + (size_t)t*2048 + hh*128 + lane*2) = b;
}

extern "C" void kernel_launch(void* const* d_in, const int* in_sizes, int n_in,
                              void* d_out, int out_size, void* d_ws, size_t ws_size,
                              hipStream_t stream) {
  const float* hs   = (const float*)d_in[0];
  const float* nw   = (const float*)d_in[1];
  const float* qw   = (const float*)d_in[2];
  const float* kw   = (const float*)d_in[3];
  const float* vw   = (const float*)d_in[4];
  const float* aw   = (const float*)d_in[5];
  const float* bw   = (const float*)d_in[6];
  const float* gw   = (const float*)d_in[7];
  const float* dtb  = (const float*)d_in[8];
  const float* alog = (const float*)d_in[9];
  const float* cqw  = (const float*)d_in[10];
  const float* ckw  = (const float*)d_in[11];
  const float* cvw  = (const float*)d_in[12];
  const float* onw  = (const float*)d_in[13];
  const float* opw  = (const float*)d_in[14];
  const float* ow   = (const float*)d_in[15];
  float* out = (float*)d_out;

  char* p = (char*)d_ws;
  auto alloc = [&](size_t bytes) { char* r = p; p += (bytes + 255) & ~255ull; return r; };
  float* xf    = (float*)alloc((size_t)2048*1024*4);
  bf16*  xb    = (bf16*) alloc((size_t)2048*1024*2);
  bf16*  qwb   = (bf16*) alloc((size_t)1024*1024*2);
  bf16*  kwb   = (bf16*) alloc((size_t)1024*1024*2);
  bf16*  vwb   = (bf16*) alloc((size_t)2048*1024*2);
  bf16*  gwb   = (bf16*) alloc((size_t)2048*1024*2);
  bf16*  opwb  = (bf16*) alloc((size_t)1024*2048*2);
  bf16*  owb   = (bf16*) alloc((size_t)1024*1024*2);
  float* qpre  = (float*)alloc((size_t)2048*1024*4);
  float* kpre  = (float*)alloc((size_t)2048*1024*4);
  float* vpre  = (float*)alloc((size_t)2048*2048*4);
  float* gpre  = (float*)alloc((size_t)2048*2048*4);
  float* qpost = (float*)alloc((size_t)2048*1024*4);
  float* kpost = (float*)alloc((size_t)2048*1024*4);
  float* vpost = (float*)alloc((size_t)2048*2048*4);
  float* graw  = (float*)alloc((size_t)2048*16*4);
  float* btb   = (float*)alloc((size_t)2048*16*4);
  float* ob    = (float*)alloc((size_t)2048*2048*4);
  bf16*  ogb   = (bf16*) alloc((size_t)2048*2048*2);
  bf16*  h1b   = (bf16*) alloc((size_t)2048*1024*2);

  // aliases for chunked-scan buffers (re-use dead fp32 intermediates):
  float* Eb  = qpre;           // 512*4096*4 = 8 MB  (qpre dead after k_convqk)
  float* Fb  = kpre;           // 512*4096*4 = 8 MB  (kpre dead after k_convqk)
  float* dSl = vpre;           // 512*8192*4 = 16 MB (vpre dead after k_convv)
  float* Sc  = qpost;          // 512*8192*4 = 16 MB spans qpost+kpost (dead after k_prepass)

  k_rmsnorm<<<2048, 256, 0, stream>>>(hs, nw, xf, xb);
  k_castw<<<4608, 256, 0, stream>>>(qw, kw, vw, gw, opw, ow, qwb, kwb, vwb, gwb, opwb, owb);
  k_gemm_proj<<<dim3(16,16,4), 256, 0, stream>>>(xb, qwb, kwb, vwb, gwb, qpre, kpre, vpre, gpre);
  k_ab<<<2048, 64, 0, stream>>>(xf, aw, bw, dtb, alog, graw, btb);
  k_convqk<<<dim3(2048,4,2), 256, 0, stream>>>(qpre, kpre, cqw, ckw, qpost, kpost);
  k_convv<<<dim3(2048,2,1), 256, 0, stream>>>(vpre, cvw, vpost);
  k_prepass<<<512, 512, 0, stream>>>(qpost, kpost, vpost, graw, btb, Eb, Fb, dSl, ob);
  k_seq<<<128, 256, 0, stream>>>(Eb, dSl, Sc);
  k_opass<<<512, 256, 0, stream>>>(Fb, Sc, ob);
  k_gatenorm<<<dim3(2048,16,1), 64, 0, stream>>>(ob, gpre, onw, ogb);
  k_gemm_bt<bf16><<<dim3(8,16,1), 256, 0, stream>>>(ogb, opwb, h1b, 1024, 2048);
  k_gemm_bt<float><<<dim3(8,16,1), 256, 0, stream>>>(h1b, owb, out, 1024, 1024);
}

// Round 4
// 405.750 us; speedup vs baseline: 2.7947x; 1.3609x over previous
//
#include <hip/hip_runtime.h>
#include <math.h>

#define TT 2048

typedef __bf16 bf16;
typedef __bf16 bf16x8 __attribute__((ext_vector_type(8)));
typedef __bf16 bf16x4v __attribute__((ext_vector_type(4)));
typedef __bf16 bf16x2v __attribute__((ext_vector_type(2)));
typedef float f32x4 __attribute__((ext_vector_type(4)));

__device__ __forceinline__ float wredsum(float v) {
#pragma unroll
  for (int off = 32; off > 0; off >>= 1) v += __shfl_xor(v, off, 64);
  return v;
}
__device__ __forceinline__ float sigmoidf_(float x) { return 1.f / (1.f + __expf(-x)); }

// ---------------- RMSNorm: h[2048,1024] -> xf (f32), xb (bf16) ----------------
__global__ __launch_bounds__(256) void k_rmsnorm(const float* __restrict__ h,
    const float* __restrict__ nw, float* __restrict__ xf, bf16* __restrict__ xb) {
  int t = blockIdx.x, tid = threadIdx.x;
  float4 hv = *(const float4*)(h + (size_t)t*1024 + tid*4);
  float ss = hv.x*hv.x + hv.y*hv.y + hv.z*hv.z + hv.w*hv.w;
  __shared__ float red[4];
  float wsum = wredsum(ss);
  if ((tid & 63) == 0) red[tid >> 6] = wsum;
  __syncthreads();
  float tot = red[0] + red[1] + red[2] + red[3];
  float rs = rsqrtf(tot * (1.f/1024.f) + 1e-6f);
  float4 w4 = *(const float4*)(nw + tid*4);
  float4 y;
  y.x = hv.x*rs*w4.x; y.y = hv.y*rs*w4.y; y.z = hv.z*rs*w4.z; y.w = hv.w*rs*w4.w;
  *(float4*)(xf + (size_t)t*1024 + tid*4) = y;
  bf16x4v b; b[0]=(bf16)y.x; b[1]=(bf16)y.y; b[2]=(bf16)y.z; b[3]=(bf16)y.w;
  *(bf16x4v*)(xb + (size_t)t*1024 + tid*4) = b;
}

// ---------------- cast weights f32 -> bf16 (6 tensors) ----------------
__global__ void k_castw(const float* __restrict__ qw, const float* __restrict__ kw,
    const float* __restrict__ vw, const float* __restrict__ gw,
    const float* __restrict__ opw, const float* __restrict__ ow,
    bf16* qwb, bf16* kwb, bf16* vwb, bf16* gwb, bf16* opwb, bf16* owb) {
  for (long u = (long)blockIdx.x*256 + threadIdx.x; u < 2359296; u += (long)gridDim.x*256) {
    const float* src; bf16* dst; long l;
    if      (u <  262144) { src=qw;  dst=qwb;  l=u; }
    else if (u <  524288) { src=kw;  dst=kwb;  l=u-262144; }
    else if (u < 1048576) { src=vw;  dst=vwb;  l=u-524288; }
    else if (u < 1572864) { src=gw;  dst=gwb;  l=u-1048576; }
    else if (u < 2097152) { src=opw; dst=opwb; l=u-1572864; }
    else                  { src=ow;  dst=owb;  l=u-2097152; }
    float4 s = *(const float4*)(src + l*4);
    bf16x4v b; b[0]=(bf16)s.x; b[1]=(bf16)s.y; b[2]=(bf16)s.z; b[3]=(bf16)s.w;
    *(bf16x4v*)(dst + l*4) = b;
  }
}

// ---------------- bf16 MFMA GEMM: C[M,N] = A[M,K] * B[N,K]^T ----------------
template <typename OutT>
__device__ __forceinline__ void gemm_body(const bf16* __restrict__ A,
    const bf16* __restrict__ B, OutT* __restrict__ C, int N, int K, int m0, int n0) {
  __shared__ bf16 As[128*32];
  __shared__ bf16 Bs[128*32];
  const int tid = threadIdx.x, lane = tid & 63, wave = tid >> 6;
  const int wm = (wave >> 1) * 64, wn = (wave & 1) * 64;
  const int srow = wave*16 + (lane >> 2);
  const int skk = (lane & 3) * 8;
  const int quad = lane >> 4, l16 = lane & 15;
  f32x4 acc[4][4] = {};
  for (int k0 = 0; k0 < K; k0 += 32) {
    __syncthreads();
#pragma unroll
    for (int i = 0; i < 2; ++i) {
      int r = i*64 + srow;
      __builtin_amdgcn_global_load_lds(
        (__attribute__((address_space(1))) void*)(A + (size_t)(m0 + r)*K + k0 + skk),
        (__attribute__((address_space(3))) void*)(As + r*32 + skk), 16, 0, 0);
      __builtin_amdgcn_global_load_lds(
        (__attribute__((address_space(1))) void*)(B + (size_t)(n0 + r)*K + k0 + skk),
        (__attribute__((address_space(3))) void*)(Bs + r*32 + skk), 16, 0, 0);
    }
    __syncthreads();
    bf16x8 af[4], bfr[4];
#pragma unroll
    for (int mt = 0; mt < 4; ++mt)
      af[mt] = *(const bf16x8*)(As + (wm + mt*16 + l16)*32 + quad*8);
#pragma unroll
    for (int nt = 0; nt < 4; ++nt)
      bfr[nt] = *(const bf16x8*)(Bs + (wn + nt*16 + l16)*32 + quad*8);
#pragma unroll
    for (int mt = 0; mt < 4; ++mt)
#pragma unroll
      for (int nt = 0; nt < 4; ++nt)
        acc[mt][nt] = __builtin_amdgcn_mfma_f32_16x16x32_bf16(af[mt], bfr[nt], acc[mt][nt], 0, 0, 0);
  }
#pragma unroll
  for (int mt = 0; mt < 4; ++mt)
#pragma unroll
    for (int nt = 0; nt < 4; ++nt)
#pragma unroll
      for (int r = 0; r < 4; ++r) {
        int row = m0 + wm + mt*16 + quad*4 + r;
        int col = n0 + wn + nt*16 + l16;
        C[(size_t)row*N + col] = (OutT)acc[mt][nt][r];
      }
}

__global__ __launch_bounds__(256) void k_gemm_proj(const bf16* __restrict__ A,
    const bf16* __restrict__ qwb, const bf16* __restrict__ kwb,
    const bf16* __restrict__ vwb, const bf16* __restrict__ gwb,
    float* __restrict__ qpre, float* __restrict__ kpre,
    float* __restrict__ vpre, float* __restrict__ gpre) {
  int z = blockIdx.z;
  const bf16* B; float* C; int N;
  if      (z == 0) { B = qwb; C = qpre; N = 1024; }
  else if (z == 1) { B = kwb; C = kpre; N = 1024; }
  else if (z == 2) { B = vwb; C = vpre; N = 2048; }
  else             { B = gwb; C = gpre; N = 2048; }
  if ((int)blockIdx.x * 128 >= N) return;
  gemm_body<float>(A, B, C, N, 1024, blockIdx.y*128, blockIdx.x*128);
}

template <typename OutT>
__global__ __launch_bounds__(256) void k_gemm_bt(const bf16* __restrict__ A,
    const bf16* __restrict__ B, OutT* __restrict__ C, int N, int K) {
  gemm_body<OutT>(A, B, C, N, K, blockIdx.y*128, blockIdx.x*128);
}

// ---------------- a/b projections (fp32) -> g (log decay), beta ----------------
__global__ __launch_bounds__(64) void k_ab(const float* __restrict__ xf,
    const float* __restrict__ aw, const float* __restrict__ bw,
    const float* __restrict__ dtb, const float* __restrict__ alog,
    float* __restrict__ graw, float* __restrict__ beta) {
  int t = blockIdx.x, lane = threadIdx.x;
  __shared__ __align__(16) float xs[1024];
#pragma unroll
  for (int i = 0; i < 16; ++i) xs[i*64 + lane] = xf[(size_t)t*1024 + i*64 + lane];
  __syncthreads();
  const float4* x4 = (const float4*)xs;
  for (int hh = 0; hh < 16; ++hh) {
    float sa = 0.f, sb = 0.f;
#pragma unroll
    for (int i = 0; i < 4; ++i) {
      float4 xv = x4[i*64 + lane];
      float4 av = *(const float4*)(aw + hh*1024 + i*256 + lane*4);
      float4 bv = *(const float4*)(bw + hh*1024 + i*256 + lane*4);
      sa += xv.x*av.x + xv.y*av.y + xv.z*av.z + xv.w*av.w;
      sb += xv.x*bv.x + xv.y*bv.y + xv.z*bv.z + xv.w*bv.w;
    }
    sa = wredsum(sa); sb = wredsum(sb);
    if (lane == 0) {
      float ap = sa + dtb[hh];
      float sp = (ap > 20.f) ? ap : log1pf(expf(ap));
      graw[t*16 + hh] = -expf(alog[hh]) * sp;
      beta[t*16 + hh] = 1.f / (1.f + expf(-sb));
    }
  }
}

// ---------------- conv(K=4)+silu for q,k + per-head postprocessing ----------------
__global__ __launch_bounds__(256) void k_convqk(const float* __restrict__ qpre,
    const float* __restrict__ kpre, const float* __restrict__ cqw,
    const float* __restrict__ ckw, float* __restrict__ qpost, float* __restrict__ kpost) {
  int t = blockIdx.x, cb = blockIdx.y, isk = blockIdx.z;
  int c = cb*256 + threadIdx.x;
  const float* in = isk ? kpre : qpre;
  const float* w  = isk ? ckw : cqw;
  float4 wv = *(const float4*)(w + c*4);
  float y = 0.f;
  int tt = t - 3;
  if (tt     >= 0) y += in[(size_t)(tt  )*1024 + c] * wv.x;
  if (tt + 1 >= 0) y += in[(size_t)(tt+1)*1024 + c] * wv.y;
  if (tt + 2 >= 0) y += in[(size_t)(tt+2)*1024 + c] * wv.z;
  y += in[(size_t)t*1024 + c] * wv.w;
  y = y * sigmoidf_(y);
  if (isk) {
    float m = wredsum(y) * (1.f/64.f);
    y -= m;
    float ss = wredsum(y*y);
    y *= rsqrtf(ss + 1e-6f);
    kpost[(size_t)t*1024 + c] = y;
  } else {
    float ss = wredsum(y*y);
    y *= rsqrtf(ss + 1e-6f) * 0.125f;
    qpost[(size_t)t*1024 + c] = y;
  }
}

// ---------------- conv(K=4)+silu for v ----------------
__global__ __launch_bounds__(256) void k_convv(const float* __restrict__ vpre,
    const float* __restrict__ cvw, float* __restrict__ vpost) {
  int t = blockIdx.x;
  int c0 = blockIdx.y*1024 + threadIdx.x*4;
  float a0=0.f, a1=0.f, a2=0.f, a3=0.f;
#pragma unroll
  for (int i = 0; i < 4; ++i) {
    int tt = t - 3 + i;
    if (tt < 0) continue;
    float4 in4 = *(const float4*)(vpre + (size_t)tt*2048 + c0);
    a0 += in4.x * cvw[(c0+0)*4 + i];
    a1 += in4.y * cvw[(c0+1)*4 + i];
    a2 += in4.z * cvw[(c0+2)*4 + i];
    a3 += in4.w * cvw[(c0+3)*4 + i];
  }
  float4 o4;
  o4.x = a0 * sigmoidf_(a0); o4.y = a1 * sigmoidf_(a1);
  o4.z = a2 * sigmoidf_(a2); o4.w = a3 * sigmoidf_(a3);
  *(float4*)(vpost + (size_t)t*2048 + c0) = o4;
}

// ---------------- MFMA chunked delta-rule pre-pass ----------------
// grid 512 = 32 chunks x 16 heads, 512 threads (8 waves: 4 row-bands x 2 col-halves).
// EF layout (bf16): per bx 13824 elems: [E_hi 64x72 | E_lo 64x72 | F 64x72]
#define S72 72

template<int NT>
__device__ __forceinline__ void mm_band(const bf16* A_lds, const bf16* B_lds,
    int w16, int cb, int l16, int quad, f32x4* acc) {
#pragma unroll
  for (int n = 0; n < NT; ++n) { acc[n][0]=0.f; acc[n][1]=0.f; acc[n][2]=0.f; acc[n][3]=0.f; }
#pragma unroll
  for (int kt = 0; kt < 2; ++kt) {
    bf16x8 af = *(const bf16x8*)(A_lds + (w16 + l16)*S72 + kt*32 + quad*8);
#pragma unroll
    for (int n = 0; n < NT; ++n) {
      bf16x8 bf = *(const bf16x8*)(B_lds + (cb + n*16 + l16)*S72 + kt*32 + quad*8);
      acc[n] = __builtin_amdgcn_mfma_f32_16x16x32_bf16(af, bf, acc[n], 0, 0, 0);
    }
  }
}

__device__ __forceinline__ bf16x8 ldg_frag(const float* p) {
  float4 a = *(const float4*)p;
  float4 b = *(const float4*)(p + 4);
  bf16x8 r;
  r[0]=(bf16)a.x; r[1]=(bf16)a.y; r[2]=(bf16)a.z; r[3]=(bf16)a.w;
  r[4]=(bf16)b.x; r[5]=(bf16)b.y; r[6]=(bf16)b.z; r[7]=(bf16)b.w;
  return r;
}

__global__ __launch_bounds__(512) void k_prepass(
    const float* __restrict__ q, const float* __restrict__ k,
    const float* __restrict__ v, const float* __restrict__ graw,
    const float* __restrict__ beta,
    bf16* __restrict__ EF, float* __restrict__ dSl, float* __restrict__ obuf) {
  const int bx = blockIdx.x, c = bx >> 4, h = bx & 15, tid = threadIdx.x;
  const int t0 = c * 64;
  const int wave = tid >> 6, lane = tid & 63, l16 = lane & 15, quad = lane >> 4;
  const int w16 = (wave >> 1) * 16;   // row band
  const int chh = wave & 1;           // column half

  __shared__ bf16 SM[50688];          // 101376 B
  __shared__ float bs[64], bts_s[64], es[64], gms[64];
  bf16* Kr    = SM;                   // K row-major [t][i]
  bf16* KT    = SM + 4608;            // K^T [i][t]
  bf16* KbT   = SM + 9216;            // es[t]*K[t][i] at [i][t]
  bf16* Pm    = SM + 13824;           // P row-major [t][s]
  bf16* powR0 = SM + 18432;
  bf16* powT0 = SM + 23040;
  bf16* powR1 = SM + 27648;
  bf16* powT1 = SM + 32256;
  bf16* prod0 = SM + 36864;
  bf16* prod1 = SM + 41472;
  bf16* T2T   = SM + 46080;           // [j][s] = beta_j*gamma_j*M[s][j]
  bf16* VT    = SM + 18432;           // alias pow0 region: [j][t] = beta_t*v[t][j]
  bf16* VlT   = SM + 27648;           // alias pow1 region: V_loc^T [j][t]

  // phase 0: decay prefix + beta (wave 0)
  if (tid < 64) {
    float g = graw[(size_t)(t0 + tid)*16 + h];
    float b = g;
#pragma unroll
    for (int off = 1; off < 64; off <<= 1) {
      float p = __shfl_up(b, off, 64);
      if (tid >= off) b += p;
    }
    bs[tid] = b;
    bts_s[tid] = beta[(size_t)(t0 + tid)*16 + h];
    float b63 = __shfl(b, 63, 64);
    es[tid] = __expf(b63 - b);
    gms[tid] = __expf(b);
  }
  __syncthreads();

  // K load: build Kr, KT, KbT
  for (int idx = tid; idx < 4096; idx += 512) {
    int t = idx >> 6, i = idx & 63;
    float kv = k[(size_t)(t0 + t)*1024 + h*64 + i];
    bf16 kb = (bf16)kv;
    Kr[t*S72 + i] = kb;
    KT[i*S72 + t] = kb;
    KbT[i*S72 + t] = (bf16)(kv * es[t]);
  }
  __syncthreads();

  // A-build: N = -A from K K^T; also prod0 = I + N
  {
    f32x4 acc[2];
    mm_band<2>(Kr, Kr, w16, chh*32, l16, quad, acc);
#pragma unroll
    for (int n = 0; n < 2; ++n) {
      int col = chh*32 + n*16 + l16;
      bf16x4v tv;
#pragma unroll
      for (int r = 0; r < 4; ++r) {
        int row = w16 + quad*4 + r;
        float nv = 0.f;
        if (row > col) nv = -bts_s[row] * __expf(bs[row] - bs[col]) * acc[n][r];
        bf16 nb = (bf16)nv;
        powR0[row*S72 + col] = nb;
        tv[r] = nb;
        prod0[row*S72 + col] = (row == col) ? (bf16)1.f : nb;
      }
      *(bf16x4v*)(powT0 + col*S72 + w16 + quad*4) = tv;
    }
  }
  // P-build: P[t][s] = exp(b_t-b_s) q_t.k_s (s<=t), q fragments from global
  {
    f32x4 acc[2];
#pragma unroll
    for (int n = 0; n < 2; ++n) { acc[n][0]=0.f; acc[n][1]=0.f; acc[n][2]=0.f; acc[n][3]=0.f; }
#pragma unroll
    for (int kt = 0; kt < 2; ++kt) {
      bf16x8 af = ldg_frag(q + (size_t)(t0 + w16 + l16)*1024 + h*64 + kt*32 + quad*8);
#pragma unroll
      for (int n = 0; n < 2; ++n) {
        bf16x8 bf = *(const bf16x8*)(Kr + (chh*32 + n*16 + l16)*S72 + kt*32 + quad*8);
        acc[n] = __builtin_amdgcn_mfma_f32_16x16x32_bf16(af, bf, acc[n], 0, 0, 0);
      }
    }
#pragma unroll
    for (int n = 0; n < 2; ++n) {
      int col = chh*32 + n*16 + l16;
#pragma unroll
      for (int r = 0; r < 4; ++r) {
        int row = w16 + quad*4 + r;
        float pv = (row >= col) ? __expf(bs[row] - bs[col]) * acc[n][r] : 0.f;
        Pm[row*S72 + col] = (bf16)pv;
      }
    }
  }
  __syncthreads();

  // squaring product chain: (I+A)^-1 = prod (I + N^(2^i))
  int pc = 0, rc = 0;
#pragma unroll 1
  for (int i = 1; i <= 5; ++i) {
    bf16* sqA = pc ? powR1 : powR0;
    bf16* sqB = pc ? powT1 : powT0;
    bf16* sqRo = pc ? powR0 : powR1;
    bf16* sqTo = pc ? powT0 : powT1;
    {
      f32x4 acc[2];
      mm_band<2>(sqA, sqB, w16, chh*32, l16, quad, acc);
#pragma unroll
      for (int n = 0; n < 2; ++n) {
        int col = chh*32 + n*16 + l16;
        bf16x4v tv;
#pragma unroll
        for (int r = 0; r < 4; ++r) {
          int row = w16 + quad*4 + r;
          bf16 vb = (bf16)acc[n][r];
          sqRo[row*S72 + col] = vb;
          tv[r] = vb;
        }
        *(bf16x4v*)(sqTo + col*S72 + w16 + quad*4) = tv;
      }
    }
    __syncthreads();
    bf16* prA = rc ? prod1 : prod0;
    bf16* prO = rc ? prod0 : prod1;
    {
      f32x4 acc[2];
      mm_band<2>(prA, sqTo, w16, chh*32, l16, quad, acc);
#pragma unroll
      for (int n = 0; n < 2; ++n) {
        int col = chh*32 + n*16 + l16;
        bf16x4v tv;
#pragma unroll
        for (int r = 0; r < 4; ++r) {
          int row = w16 + quad*4 + r;
          float val = acc[n][r] + (float)prA[row*S72 + col];
          prO[row*S72 + col] = (bf16)val;
          tv[r] = (bf16)(val * bts_s[col] * gms[col]);
        }
        if (i == 5) *(bf16x4v*)(T2T + col*S72 + w16 + quad*4) = tv;
      }
    }
    __syncthreads();
    pc ^= 1; rc ^= 1;
  }
  bf16* Mrow = rc ? prod1 : prod0;
  bf16* WR   = rc ? prod0 : prod1;

  // VT build (aliases pow0 region, now dead): VT[j][t] = beta_t * v[t][j]
  for (int idx = tid; idx < 8192; idx += 512) {
    int t = idx >> 7, j = idx & 127;
    VT[j*S72 + t] = (bf16)(bts_s[t] * v[(size_t)(t0 + t)*2048 + h*128 + j]);
  }
  __syncthreads();

  // V_loc = M (beta V): write V_loc^T
  {
    f32x4 acc[4];
    mm_band<4>(Mrow, VT, w16, chh*64, l16, quad, acc);
#pragma unroll
    for (int n = 0; n < 4; ++n) {
      int col = chh*64 + n*16 + l16;
      bf16x4v tv;
#pragma unroll
      for (int r = 0; r < 4; ++r) tv[r] = (bf16)acc[n][r];
      *(bf16x4v*)(VlT + col*S72 + w16 + quad*4) = tv;
    }
  }
  __syncthreads();

  // dS_loc = Kbar^T V_loc -> global (fp32)
  {
    f32x4 acc[4];
    mm_band<4>(KbT, VlT, w16, chh*64, l16, quad, acc);
#pragma unroll
    for (int n = 0; n < 4; ++n) {
      int col = chh*64 + n*16 + l16;
#pragma unroll
      for (int r = 0; r < 4; ++r)
        dSl[(size_t)bx*8192 + (size_t)(w16 + quad*4 + r)*128 + col] = acc[n][r];
    }
  }
  // W2 = Kbar^T T2 -> WR (bf16 row-major)
  {
    f32x4 acc[2];
    mm_band<2>(KbT, T2T, w16, chh*32, l16, quad, acc);
#pragma unroll
    for (int n = 0; n < 2; ++n) {
      int col = chh*32 + n*16 + l16;
#pragma unroll
      for (int r = 0; r < 4; ++r)
        WR[(w16 + quad*4 + r)*S72 + col] = (bf16)acc[n][r];
    }
  }
  __syncthreads();
  // E = gamma_C I - W2 K -> EF planes 0 (hi) and 1 (lo)
  {
    f32x4 acc[2];
    mm_band<2>(WR, KT, w16, chh*32, l16, quad, acc);
    float gC = gms[63];
    size_t eb = (size_t)bx * 13824;
#pragma unroll
    for (int n = 0; n < 2; ++n) {
      int col = chh*32 + n*16 + l16;
#pragma unroll
      for (int r = 0; r < 4; ++r) {
        int row = w16 + quad*4 + r;
        float ev = ((row == col) ? gC : 0.f) - acc[n][r];
        bf16 eh = (bf16)ev;
        EF[eb + row*S72 + col] = eh;
        EF[eb + 4608 + row*S72 + col] = (bf16)(ev - (float)eh);
      }
    }
  }
  __syncthreads();   // E's reads of WR done before R overwrites
  // R = P T2 -> WR
  {
    f32x4 acc[2];
    mm_band<2>(Pm, T2T, w16, chh*32, l16, quad, acc);
#pragma unroll
    for (int n = 0; n < 2; ++n) {
      int col = chh*32 + n*16 + l16;
#pragma unroll
      for (int r = 0; r < 4; ++r)
        WR[(w16 + quad*4 + r)*S72 + col] = (bf16)acc[n][r];
    }
  }
  __syncthreads();
  // F = diag(gamma) Q - R K -> EF plane 2
  {
    f32x4 acc[2];
    mm_band<2>(WR, KT, w16, chh*32, l16, quad, acc);
    size_t eb = (size_t)bx * 13824;
#pragma unroll
    for (int n = 0; n < 2; ++n) {
      int col = chh*32 + n*16 + l16;
#pragma unroll
      for (int r = 0; r < 4; ++r) {
        int row = w16 + quad*4 + r;
        float qv = q[(size_t)(t0 + row)*1024 + h*64 + col];
        EF[eb + 9216 + row*S72 + col] = (bf16)(gms[row]*qv - acc[n][r]);
      }
    }
  }
  // O_loc = P V_loc -> global
  {
    f32x4 acc[4];
    mm_band<4>(Pm, VlT, w16, chh*64, l16, quad, acc);
#pragma unroll
    for (int n = 0; n < 4; ++n) {
      int col = chh*64 + n*16 + l16;
#pragma unroll
      for (int r = 0; r < 4; ++r)
        obuf[(size_t)(t0 + w16 + quad*4 + r)*2048 + h*128 + col] = acc[n][r];
    }
  }
}

// ---------------- MFMA sequential recurrence + output (fused k_opass) ----------------
// grid 64 = 16 heads x 4 dv-quarters (32 wide). 256 threads (4 waves, m-bands of 16).
// Per chunk: accS = E_c S_c + dS_c ; O_c = F_c S_c (S_c = state at chunk start).
// S in LDS transposed bf16 hi/lo pair (fp24-equiv). E hi/lo, F bf16, DMA'd double-buffered.
__global__ __launch_bounds__(256) void k_seq(const bf16* __restrict__ EF,
    const float* __restrict__ dSl, float* __restrict__ osb) {
  const int h = blockIdx.x >> 2, dq = blockIdx.x & 3;
  const int tid = threadIdx.x, wave = tid >> 6, lane = tid & 63;
  const int l16 = lane & 15, quad = lane >> 4;
  const int mb = wave * 16;
  __shared__ bf16 ebuf[2][13824];
  __shared__ bf16 Sthi[32*S72], Stlo[32*S72];
  for (int i = tid; i < 2304; i += 256) { Sthi[i] = (bf16)0.f; Stlo[i] = (bf16)0.f; }
  // DMA chunk 0 E/F
  {
    const bf16* efg = EF + (size_t)h * 13824;
    for (int i = tid; i < 1728; i += 256)
      __builtin_amdgcn_global_load_lds(
        (__attribute__((address_space(1))) void*)(efg + i*8),
        (__attribute__((address_space(3))) void*)(&ebuf[0][i*8]), 16, 0, 0);
  }
  // dS regs chunk 0
  float dsv[8];
  {
    size_t base = (size_t)h*8192 + dq*32;
#pragma unroll
    for (int nt = 0; nt < 2; ++nt)
#pragma unroll
      for (int r = 0; r < 4; ++r)
        dsv[nt*4+r] = dSl[base + (size_t)(mb + quad*4 + r)*128 + nt*16 + l16];
  }
  __syncthreads();
#pragma unroll 1
  for (int c = 0; c < 32; ++c) {
    const int cur = c & 1, nxt = cur ^ 1;
    float dsn[8] = {};
    if (c + 1 < 32) {
      const bf16* efg = EF + (size_t)((c+1)*16 + h) * 13824;
      for (int i = tid; i < 1728; i += 256)
        __builtin_amdgcn_global_load_lds(
          (__attribute__((address_space(1))) void*)(efg + i*8),
          (__attribute__((address_space(3))) void*)(&ebuf[nxt][i*8]), 16, 0, 0);
      size_t base = (size_t)((c+1)*16 + h)*8192 + dq*32;
#pragma unroll
      for (int nt = 0; nt < 2; ++nt)
#pragma unroll
        for (int r = 0; r < 4; ++r)
          dsn[nt*4+r] = dSl[base + (size_t)(mb + quad*4 + r)*128 + nt*16 + l16];
    }
    const bf16* Eh = &ebuf[cur][0];
    const bf16* El = &ebuf[cur][4608];
    const bf16* Ff = &ebuf[cur][9216];
    // B-operand fragments from St (shared by both matmuls)
    bf16x8 bh[2][2], bl[2][2];
#pragma unroll
    for (int nt = 0; nt < 2; ++nt)
#pragma unroll
      for (int kt = 0; kt < 2; ++kt) {
        bh[nt][kt] = *(const bf16x8*)(Sthi + (nt*16 + l16)*S72 + kt*32 + quad*8);
        bl[nt][kt] = *(const bf16x8*)(Stlo + (nt*16 + l16)*S72 + kt*32 + quad*8);
      }
    f32x4 accS[2], accO[2];
#pragma unroll
    for (int nt = 0; nt < 2; ++nt) {
#pragma unroll
      for (int r = 0; r < 4; ++r) accS[nt][r] = dsv[nt*4+r];
      accO[nt][0]=0.f; accO[nt][1]=0.f; accO[nt][2]=0.f; accO[nt][3]=0.f;
    }
#pragma unroll
    for (int kt = 0; kt < 2; ++kt) {
      bf16x8 aeh = *(const bf16x8*)(Eh + (mb + l16)*S72 + kt*32 + quad*8);
      bf16x8 ael = *(const bf16x8*)(El + (mb + l16)*S72 + kt*32 + quad*8);
      bf16x8 aff = *(const bf16x8*)(Ff + (mb + l16)*S72 + kt*32 + quad*8);
#pragma unroll
      for (int nt = 0; nt < 2; ++nt) {
        accS[nt] = __builtin_amdgcn_mfma_f32_16x16x32_bf16(aeh, bh[nt][kt], accS[nt], 0, 0, 0);
        accS[nt] = __builtin_amdgcn_mfma_f32_16x16x32_bf16(aeh, bl[nt][kt], accS[nt], 0, 0, 0);
        accS[nt] = __builtin_amdgcn_mfma_f32_16x16x32_bf16(ael, bh[nt][kt], accS[nt], 0, 0, 0);
        accO[nt] = __builtin_amdgcn_mfma_f32_16x16x32_bf16(aff, bh[nt][kt], accO[nt], 0, 0, 0);
        accO[nt] = __builtin_amdgcn_mfma_f32_16x16x32_bf16(aff, bl[nt][kt], accO[nt], 0, 0, 0);
      }
    }
    __syncthreads();   // all St reads done before overwrite
    // O_c -> global
    {
      int t0 = c*64;
#pragma unroll
      for (int nt = 0; nt < 2; ++nt)
#pragma unroll
        for (int r = 0; r < 4; ++r)
          osb[(size_t)(t0 + mb + quad*4 + r)*2048 + h*128 + dq*32 + nt*16 + l16] = accO[nt][r];
    }
    // St_new (hi/lo)
#pragma unroll
    for (int nt = 0; nt < 2; ++nt) {
      bf16x4v hv, lv;
#pragma unroll
      for (int r = 0; r < 4; ++r) {
        float v = accS[nt][r];
        bf16 hb = (bf16)v;
        hv[r] = hb;
        lv[r] = (bf16)(v - (float)hb);
      }
      *(bf16x4v*)(Sthi + (nt*16 + l16)*S72 + mb + quad*4) = hv;
      *(bf16x4v*)(Stlo + (nt*16 + l16)*S72 + mb + quad*4) = lv;
    }
#pragma unroll
    for (int i = 0; i < 8; ++i) dsv[i] = dsn[i];
    __syncthreads();   // St visible + DMA drained for next chunk
  }
}

// ---------------- gated RMSNorm on o = O_loc + O_s, write bf16 ----------------
__global__ __launch_bounds__(64) void k_gatenorm(const float* __restrict__ o,
    const float* __restrict__ os, const float* __restrict__ gpre,
    const float* __restrict__ onw, bf16* __restrict__ og) {
  int t = blockIdx.x, hh = blockIdx.y, lane = threadIdx.x;
  size_t base = (size_t)t*2048 + hh*128 + lane*2;
  float2 o2 = *(const float2*)(o + base);
  float2 s2 = *(const float2*)(os + base);
  o2.x += s2.x; o2.y += s2.y;
  float ss = wredsum(o2.x*o2.x + o2.y*o2.y);
  float rs = rsqrtf(ss * (1.f/128.f) + 1e-5f);
  float2 nw = *(const float2*)(onw + lane*2);
  float2 g2 = *(const float2*)(gpre + base);
  float r0 = o2.x * rs * nw.x * (g2.x * sigmoidf_(g2.x));
  float r1 = o2.y * rs * nw.y * (g2.y * sigmoidf_(g2.y));
  bf16x2v b; b[0] = (bf16)r0; b[1] = (bf16)r1;
  *(bf16x2v*)(og + base) = b;
}

extern "C" void kernel_launch(void* const* d_in, const int* in_sizes, int n_in,
                              void* d_out, int out_size, void* d_ws, size_t ws_size,
                              hipStream_t stream) {
  const float* hs   = (const float*)d_in[0];
  const float* nw   = (const float*)d_in[1];
  const float* qw   = (const float*)d_in[2];
  const float* kw   = (const float*)d_in[3];
  const float* vw   = (const float*)d_in[4];
  const float* aw   = (const float*)d_in[5];
  const float* bw   = (const float*)d_in[6];
  const float* gw   = (const float*)d_in[7];
  const float* dtb  = (const float*)d_in[8];
  const float* alog = (const float*)d_in[9];
  const float* cqw  = (const float*)d_in[10];
  const float* ckw  = (const float*)d_in[11];
  const float* cvw  = (const float*)d_in[12];
  const float* onw  = (const float*)d_in[13];
  const float* opw  = (const float*)d_in[14];
  const float* ow   = (const float*)d_in[15];
  float* out = (float*)d_out;

  char* p = (char*)d_ws;
  auto alloc = [&](size_t bytes) { char* r = p; p += (bytes + 255) & ~255ull; return r; };
  float* xf    = (float*)alloc((size_t)2048*1024*4);
  bf16*  xb    = (bf16*) alloc((size_t)2048*1024*2);
  bf16*  qwb   = (bf16*) alloc((size_t)1024*1024*2);
  bf16*  kwb   = (bf16*) alloc((size_t)1024*1024*2);
  bf16*  vwb   = (bf16*) alloc((size_t)2048*1024*2);
  bf16*  gwb   = (bf16*) alloc((size_t)2048*1024*2);
  bf16*  opwb  = (bf16*) alloc((size_t)1024*2048*2);
  bf16*  owb   = (bf16*) alloc((size_t)1024*1024*2);
  float* qpre  = (float*)alloc((size_t)2048*1024*4);
  float* kpre  = (float*)alloc((size_t)2048*1024*4);
  float* vpre  = (float*)alloc((size_t)2048*2048*4);
  float* gpre  = (float*)alloc((size_t)2048*2048*4);
  float* qpost = (float*)alloc((size_t)2048*1024*4);
  float* kpost = (float*)alloc((size_t)2048*1024*4);
  float* vpost = (float*)alloc((size_t)2048*2048*4);
  float* graw  = (float*)alloc((size_t)2048*16*4);
  float* btb   = (float*)alloc((size_t)2048*16*4);
  float* ob    = (float*)alloc((size_t)2048*2048*4);
  bf16*  ogb   = (bf16*) alloc((size_t)2048*2048*2);
  bf16*  h1b   = (bf16*) alloc((size_t)2048*1024*2);

  // aliases for chunked-scan buffers (re-use dead fp32 intermediates):
  bf16*  EF  = (bf16*)qpre;    // 512*13824*2 = 14.2 MB over qpre+kpre (dead after k_convqk)
  float* dSl = vpre;           // 512*8192*4 = 16 MB (vpre dead after k_convv)
  float* osb = qpost;          // 16 MB over qpost+kpost (dead after k_prepass)

  k_rmsnorm<<<2048, 256, 0, stream>>>(hs, nw, xf, xb);
  k_castw<<<4608, 256, 0, stream>>>(qw, kw, vw, gw, opw, ow, qwb, kwb, vwb, gwb, opwb, owb);
  k_gemm_proj<<<dim3(16,16,4), 256, 0, stream>>>(xb, qwb, kwb, vwb, gwb, qpre, kpre, vpre, gpre);
  k_ab<<<2048, 64, 0, stream>>>(xf, aw, bw, dtb, alog, graw, btb);
  k_convqk<<<dim3(2048,4,2), 256, 0, stream>>>(qpre, kpre, cqw, ckw, qpost, kpost);
  k_convv<<<dim3(2048,2,1), 256, 0, stream>>>(vpre, cvw, vpost);
  k_prepass<<<512, 512, 0, stream>>>(qpost, kpost, vpost, graw, btb, EF, dSl, ob);
  k_seq<<<64, 256, 0, stream>>>(EF, dSl, osb);
  k_gatenorm<<<dim3(2048,16,1), 64, 0, stream>>>(ob, osb, gpre, onw, ogb);
  k_gemm_bt<bf16><<<dim3(8,16,1), 256, 0, stream>>>(ogb, opwb, h1b, 1024, 2048);
  k_gemm_bt<float><<<dim3(8,16,1), 256, 0, stream>>>(h1b, owb, out, 1024, 1024);
}

// Round 5
// 333.705 us; speedup vs baseline: 3.3981x; 1.2159x over previous
//
#include <hip/hip_runtime.h>
#include <math.h>

#define TT 2048

typedef __bf16 bf16;
typedef __bf16 bf16x8 __attribute__((ext_vector_type(8)));
typedef __bf16 bf16x4v __attribute__((ext_vector_type(4)));
typedef __bf16 bf16x2v __attribute__((ext_vector_type(2)));
typedef float f32x4 __attribute__((ext_vector_type(4)));

__device__ __forceinline__ float wredsum(float v) {
#pragma unroll
  for (int off = 32; off > 0; off >>= 1) v += __shfl_xor(v, off, 64);
  return v;
}
__device__ __forceinline__ float sigmoidf_(float x) { return 1.f / (1.f + __expf(-x)); }

// ---------------- RMSNorm + a/b projections fused ----------------
// One block per t. Writes xb (bf16 normed x), graw (log decay), btb (beta).
__global__ __launch_bounds__(256) void k_rmsnorm(const float* __restrict__ h,
    const float* __restrict__ nw, const float* __restrict__ aw,
    const float* __restrict__ bw, const float* __restrict__ dtb,
    const float* __restrict__ alog, bf16* __restrict__ xb,
    float* __restrict__ graw, float* __restrict__ btb) {
  int t = blockIdx.x, tid = threadIdx.x;
  float4 hv = *(const float4*)(h + (size_t)t*1024 + tid*4);
  float ss = hv.x*hv.x + hv.y*hv.y + hv.z*hv.z + hv.w*hv.w;
  __shared__ float red[4];
  __shared__ __align__(16) float xs[1024];
  float wsum = wredsum(ss);
  if ((tid & 63) == 0) red[tid >> 6] = wsum;
  __syncthreads();
  float tot = red[0] + red[1] + red[2] + red[3];
  float rs = rsqrtf(tot * (1.f/1024.f) + 1e-6f);
  float4 w4 = *(const float4*)(nw + tid*4);
  float4 y;
  y.x = hv.x*rs*w4.x; y.y = hv.y*rs*w4.y; y.z = hv.z*rs*w4.z; y.w = hv.w*rs*w4.w;
  *(float4*)(xs + tid*4) = y;
  bf16x4v b; b[0]=(bf16)y.x; b[1]=(bf16)y.y; b[2]=(bf16)y.z; b[3]=(bf16)y.w;
  *(bf16x4v*)(xb + (size_t)t*1024 + tid*4) = b;
  __syncthreads();
  // a/b projections: wave w handles heads 4w..4w+3
  int wave = tid >> 6, lane = tid & 63;
  const float4* x4 = (const float4*)xs;
#pragma unroll
  for (int hi = 0; hi < 4; ++hi) {
    int hh = wave*4 + hi;
    float sa = 0.f, sb = 0.f;
#pragma unroll
    for (int i = 0; i < 4; ++i) {
      float4 xv = x4[i*64 + lane];
      float4 av = *(const float4*)(aw + hh*1024 + i*256 + lane*4);
      float4 bv = *(const float4*)(bw + hh*1024 + i*256 + lane*4);
      sa += xv.x*av.x + xv.y*av.y + xv.z*av.z + xv.w*av.w;
      sb += xv.x*bv.x + xv.y*bv.y + xv.z*bv.z + xv.w*bv.w;
    }
    sa = wredsum(sa); sb = wredsum(sb);
    if (lane == 0) {
      float ap = sa + dtb[hh];
      float sp = (ap > 20.f) ? ap : log1pf(expf(ap));
      graw[t*16 + hh] = -expf(alog[hh]) * sp;
      btb[t*16 + hh] = 1.f / (1.f + expf(-sb));
    }
  }
}

// ---------------- cast weights f32 -> bf16 (6 tensors) ----------------
__global__ void k_castw(const float* __restrict__ qw, const float* __restrict__ kw,
    const float* __restrict__ vw, const float* __restrict__ gw,
    const float* __restrict__ opw, const float* __restrict__ ow,
    bf16* qwb, bf16* kwb, bf16* vwb, bf16* gwb, bf16* opwb, bf16* owb) {
  for (long u = (long)blockIdx.x*256 + threadIdx.x; u < 2359296; u += (long)gridDim.x*256) {
    const float* src; bf16* dst; long l;
    if      (u <  262144) { src=qw;  dst=qwb;  l=u; }
    else if (u <  524288) { src=kw;  dst=kwb;  l=u-262144; }
    else if (u < 1048576) { src=vw;  dst=vwb;  l=u-524288; }
    else if (u < 1572864) { src=gw;  dst=gwb;  l=u-1048576; }
    else if (u < 2097152) { src=opw; dst=opwb; l=u-1572864; }
    else                  { src=ow;  dst=owb;  l=u-2097152; }
    float4 s = *(const float4*)(src + l*4);
    bf16x4v b; b[0]=(bf16)s.x; b[1]=(bf16)s.y; b[2]=(bf16)s.z; b[3]=(bf16)s.w;
    *(bf16x4v*)(dst + l*4) = b;
  }
}

// ---------------- bf16 MFMA GEMM: C[M,N] = A[M,K] * B[N,K]^T ----------------
// XOR-swizzled LDS staging: LDS[row][chunk j] holds global chunk j ^ ((row>>1)&3)
// (swizzle applied to the GLOBAL fetch address; global_load_lds dest is lane-contiguous).
// Reads fetch chunk quad^((row>>1)&3) -> bank pattern period 8 -> 2-way = free.
template <typename OutT>
__device__ __forceinline__ void gemm_body(const bf16* __restrict__ A,
    const bf16* __restrict__ B, OutT* __restrict__ C, int N, int K, int m0, int n0) {
  __shared__ bf16 As[128*32];
  __shared__ bf16 Bs[128*32];
  const int tid = threadIdx.x, lane = tid & 63, wave = tid >> 6;
  const int wm = (wave >> 1) * 64, wn = (wave & 1) * 64;
  const int srow = wave*16 + (lane >> 2);
  const int swl = (((lane & 3) ^ ((lane >> 3) & 3))) * 8;  // swizzled global chunk
  const int sdst = (lane & 3) * 8;                          // contiguous LDS chunk
  const int quad = lane >> 4, l16 = lane & 15;
  const int sw = (l16 >> 1) & 3;                            // read-side row swizzle
  f32x4 acc[4][4] = {};
  for (int k0 = 0; k0 < K; k0 += 32) {
    __syncthreads();
#pragma unroll
    for (int i = 0; i < 2; ++i) {
      int r = i*64 + srow;
      __builtin_amdgcn_global_load_lds(
        (__attribute__((address_space(1))) void*)(A + (size_t)(m0 + r)*K + k0 + swl),
        (__attribute__((address_space(3))) void*)(As + r*32 + sdst), 16, 0, 0);
      __builtin_amdgcn_global_load_lds(
        (__attribute__((address_space(1))) void*)(B + (size_t)(n0 + r)*K + k0 + swl),
        (__attribute__((address_space(3))) void*)(Bs + r*32 + sdst), 16, 0, 0);
    }
    __syncthreads();
    bf16x8 af[4], bfr[4];
#pragma unroll
    for (int mt = 0; mt < 4; ++mt)
      af[mt] = *(const bf16x8*)(As + (wm + mt*16 + l16)*32 + (quad ^ sw)*8);
#pragma unroll
    for (int nt = 0; nt < 4; ++nt)
      bfr[nt] = *(const bf16x8*)(Bs + (wn + nt*16 + l16)*32 + (quad ^ sw)*8);
#pragma unroll
    for (int mt = 0; mt < 4; ++mt)
#pragma unroll
      for (int nt = 0; nt < 4; ++nt)
        acc[mt][nt] = __builtin_amdgcn_mfma_f32_16x16x32_bf16(af[mt], bfr[nt], acc[mt][nt], 0, 0, 0);
  }
#pragma unroll
  for (int mt = 0; mt < 4; ++mt)
#pragma unroll
    for (int nt = 0; nt < 4; ++nt)
#pragma unroll
      for (int r = 0; r < 4; ++r) {
        int row = m0 + wm + mt*16 + quad*4 + r;
        int col = n0 + wn + nt*16 + l16;
        C[(size_t)row*N + col] = (OutT)acc[mt][nt][r];
      }
}

__global__ __launch_bounds__(256) void k_gemm_proj(const bf16* __restrict__ A,
    const bf16* __restrict__ qwb, const bf16* __restrict__ kwb,
    const bf16* __restrict__ vwb, const bf16* __restrict__ gwb,
    float* __restrict__ qpre, float* __restrict__ kpre,
    float* __restrict__ vpre, float* __restrict__ gpre) {
  int z = blockIdx.z;
  const bf16* B; float* C; int N;
  if      (z == 0) { B = qwb; C = qpre; N = 1024; }
  else if (z == 1) { B = kwb; C = kpre; N = 1024; }
  else if (z == 2) { B = vwb; C = vpre; N = 2048; }
  else             { B = gwb; C = gpre; N = 2048; }
  if ((int)blockIdx.x * 128 >= N) return;
  gemm_body<float>(A, B, C, N, 1024, blockIdx.y*128, blockIdx.x*128);
}

template <typename OutT>
__global__ __launch_bounds__(256) void k_gemm_bt(const bf16* __restrict__ A,
    const bf16* __restrict__ B, OutT* __restrict__ C, int N, int K) {
  gemm_body<OutT>(A, B, C, N, K, blockIdx.y*128, blockIdx.x*128);
}

// ---------------- MFMA chunked delta-rule pre-pass (conv fused) ----------------
// grid 512 = 32 chunks x 16 heads, 512 threads (8 waves: 4 row-bands x 2 col-halves).
// Conv+silu+norm computed in-wave: wave owns 8 rows, channel = lane, wredsum = row reduce.
// EF layout (bf16): per bx 13824 elems: [E_hi 64x72 | E_lo 64x72 | F 64x72]
#define S72 72

template<int NT>
__device__ __forceinline__ void mm_band(const bf16* A_lds, const bf16* B_lds,
    int w16, int cb, int l16, int quad, f32x4* acc) {
#pragma unroll
  for (int n = 0; n < NT; ++n) { acc[n][0]=0.f; acc[n][1]=0.f; acc[n][2]=0.f; acc[n][3]=0.f; }
#pragma unroll
  for (int kt = 0; kt < 2; ++kt) {
    bf16x8 af = *(const bf16x8*)(A_lds + (w16 + l16)*S72 + kt*32 + quad*8);
#pragma unroll
    for (int n = 0; n < NT; ++n) {
      bf16x8 bf = *(const bf16x8*)(B_lds + (cb + n*16 + l16)*S72 + kt*32 + quad*8);
      acc[n] = __builtin_amdgcn_mfma_f32_16x16x32_bf16(af, bf, acc[n], 0, 0, 0);
    }
  }
}

__global__ __launch_bounds__(512) void k_prepass(
    const float* __restrict__ qpre, const float* __restrict__ kpre,
    const float* __restrict__ vpre, const float* __restrict__ cqw,
    const float* __restrict__ ckw, const float* __restrict__ cvw,
    const float* __restrict__ graw, const float* __restrict__ beta,
    bf16* __restrict__ EF, float* __restrict__ dSl, float* __restrict__ obuf) {
  const int bx = blockIdx.x, c = bx >> 4, h = bx & 15, tid = threadIdx.x;
  const int t0 = c * 64;
  const int wave = tid >> 6, lane = tid & 63, l16 = lane & 15, quad = lane >> 4;
  const int w16 = (wave >> 1) * 16;   // row band for MFMA phases
  const int chh = wave & 1;           // column half
  const int r0 = wave * 8;            // row band for conv phase

  __shared__ bf16 SM[50688];          // 101376 B
  __shared__ float qf[64*68];         // fp32 q (stride 68: 2-way banks)
  __shared__ float bs[64], bts_s[64], es[64], gms[64];
  bf16* Kr    = SM;                   // K row-major [t][i]
  bf16* KT    = SM + 4608;            // K^T [i][t]
  bf16* KbT   = SM + 9216;            // es[t]*K[t][i] at [i][t]
  bf16* Pm    = SM + 13824;           // P row-major [t][s]
  bf16* powR0 = SM + 18432;
  bf16* powT0 = SM + 23040;
  bf16* powR1 = SM + 27648;
  bf16* powT1 = SM + 32256;
  bf16* prod0 = SM + 36864;
  bf16* prod1 = SM + 41472;
  bf16* T2T   = SM + 46080;           // [j][s] = beta_j*gamma_j*M[s][j]
  bf16* VT    = SM + 18432;           // alias pow0 region: [j][t] = beta_t*v[t][j]
  bf16* VlT   = SM + 27648;           // alias pow1 region: V_loc^T [j][t]

  // decay prefix + beta (wave 0; other waves run ahead into conv)
  if (tid < 64) {
    float g = graw[(size_t)(t0 + tid)*16 + h];
    float b = g;
#pragma unroll
    for (int off = 1; off < 64; off <<= 1) {
      float p = __shfl_up(b, off, 64);
      if (tid >= off) b += p;
    }
    bs[tid] = b;
    bts_s[tid] = beta[(size_t)(t0 + tid)*16 + h];
    float b63 = __shfl(b, 63, 64);
    es[tid] = __expf(b63 - b);
    gms[tid] = __expf(b);
  }

  // fused causal conv(K=4)+silu+norms
  float kreg[8], vreg[16];
  {
    float4 wq  = *(const float4*)(cqw + (h*64 + lane)*4);
    float4 wk  = *(const float4*)(ckw + (h*64 + lane)*4);
    float tv[11];
#pragma unroll
    for (int j = 0; j < 11; ++j) {
      int tg = t0 + r0 + j - 3;
      tv[j] = (tg >= 0) ? qpre[(size_t)tg*1024 + h*64 + lane] : 0.f;
    }
#pragma unroll
    for (int rr = 0; rr < 8; ++rr) {
      float y = tv[rr]*wq.x + tv[rr+1]*wq.y + tv[rr+2]*wq.z + tv[rr+3]*wq.w;
      y = y * sigmoidf_(y);
      float ssq = wredsum(y*y);
      y *= rsqrtf(ssq + 1e-6f) * 0.125f;          // L2 norm * DK^-0.5
      qf[(r0+rr)*68 + lane] = y;
    }
#pragma unroll
    for (int j = 0; j < 11; ++j) {
      int tg = t0 + r0 + j - 3;
      tv[j] = (tg >= 0) ? kpre[(size_t)tg*1024 + h*64 + lane] : 0.f;
    }
#pragma unroll
    for (int rr = 0; rr < 8; ++rr) {
      float y = tv[rr]*wk.x + tv[rr+1]*wk.y + tv[rr+2]*wk.z + tv[rr+3]*wk.w;
      y = y * sigmoidf_(y);
      float m = wredsum(y) * (1.f/64.f);          // rank-1 DC removal
      y -= m;
      float ssq = wredsum(y*y);
      y *= rsqrtf(ssq + 1e-6f);
      kreg[rr] = y;
      bf16 kb = (bf16)y;
      Kr[(r0+rr)*S72 + lane] = kb;
      KT[lane*S72 + (r0+rr)] = kb;
    }
#pragma unroll
    for (int hf = 0; hf < 2; ++hf) {
      float4 wv = *(const float4*)(cvw + (h*128 + hf*64 + lane)*4);
#pragma unroll
      for (int j = 0; j < 11; ++j) {
        int tg = t0 + r0 + j - 3;
        tv[j] = (tg >= 0) ? vpre[(size_t)tg*2048 + h*128 + hf*64 + lane] : 0.f;
      }
#pragma unroll
      for (int rr = 0; rr < 8; ++rr) {
        float y = tv[rr]*wv.x + tv[rr+1]*wv.y + tv[rr+2]*wv.z + tv[rr+3]*wv.w;
        vreg[hf*8+rr] = y * sigmoidf_(y);
      }
    }
  }
  __syncthreads();
  // KbT from kreg (needs es)
#pragma unroll
  for (int rr = 0; rr < 8; ++rr)
    KbT[lane*S72 + (r0+rr)] = (bf16)(kreg[rr] * es[r0+rr]);

  // A-build: N = -A from K K^T; also prod0 = I + N
  {
    f32x4 acc[2];
    mm_band<2>(Kr, Kr, w16, chh*32, l16, quad, acc);
#pragma unroll
    for (int n = 0; n < 2; ++n) {
      int col = chh*32 + n*16 + l16;
      bf16x4v tv;
#pragma unroll
      for (int r = 0; r < 4; ++r) {
        int row = w16 + quad*4 + r;
        float nv = 0.f;
        if (row > col) nv = -bts_s[row] * __expf(bs[row] - bs[col]) * acc[n][r];
        bf16 nb = (bf16)nv;
        powR0[row*S72 + col] = nb;
        tv[r] = nb;
        prod0[row*S72 + col] = (row == col) ? (bf16)1.f : nb;
      }
      *(bf16x4v*)(powT0 + col*S72 + w16 + quad*4) = tv;
    }
  }
  // P-build: P[t][s] = exp(b_t-b_s) q_t.k_s (s<=t), q frags from qf LDS
  {
    f32x4 acc[2];
#pragma unroll
    for (int n = 0; n < 2; ++n) { acc[n][0]=0.f; acc[n][1]=0.f; acc[n][2]=0.f; acc[n][3]=0.f; }
#pragma unroll
    for (int kt = 0; kt < 2; ++kt) {
      const float* qp = qf + (w16 + l16)*68 + kt*32 + quad*8;
      float4 a4 = *(const float4*)qp;
      float4 b4 = *(const float4*)(qp + 4);
      bf16x8 af;
      af[0]=(bf16)a4.x; af[1]=(bf16)a4.y; af[2]=(bf16)a4.z; af[3]=(bf16)a4.w;
      af[4]=(bf16)b4.x; af[5]=(bf16)b4.y; af[6]=(bf16)b4.z; af[7]=(bf16)b4.w;
#pragma unroll
      for (int n = 0; n < 2; ++n) {
        bf16x8 bf = *(const bf16x8*)(Kr + (chh*32 + n*16 + l16)*S72 + kt*32 + quad*8);
        acc[n] = __builtin_amdgcn_mfma_f32_16x16x32_bf16(af, bf, acc[n], 0, 0, 0);
      }
    }
#pragma unroll
    for (int n = 0; n < 2; ++n) {
      int col = chh*32 + n*16 + l16;
#pragma unroll
      for (int r = 0; r < 4; ++r) {
        int row = w16 + quad*4 + r;
        float pv = (row >= col) ? __expf(bs[row] - bs[col]) * acc[n][r] : 0.f;
        Pm[row*S72 + col] = (bf16)pv;
      }
    }
  }
  __syncthreads();

  // squaring product chain: (I+A)^-1 = prod (I + N^(2^i))
  int pc = 0, rc = 0;
#pragma unroll 1
  for (int i = 1; i <= 5; ++i) {
    bf16* sqA = pc ? powR1 : powR0;
    bf16* sqB = pc ? powT1 : powT0;
    bf16* sqRo = pc ? powR0 : powR1;
    bf16* sqTo = pc ? powT0 : powT1;
    {
      f32x4 acc[2];
      mm_band<2>(sqA, sqB, w16, chh*32, l16, quad, acc);
#pragma unroll
      for (int n = 0; n < 2; ++n) {
        int col = chh*32 + n*16 + l16;
        bf16x4v tv;
#pragma unroll
        for (int r = 0; r < 4; ++r) {
          int row = w16 + quad*4 + r;
          bf16 vb = (bf16)acc[n][r];
          sqRo[row*S72 + col] = vb;
          tv[r] = vb;
        }
        *(bf16x4v*)(sqTo + col*S72 + w16 + quad*4) = tv;
      }
    }
    __syncthreads();
    bf16* prA = rc ? prod1 : prod0;
    bf16* prO = rc ? prod0 : prod1;
    {
      f32x4 acc[2];
      mm_band<2>(prA, sqTo, w16, chh*32, l16, quad, acc);
#pragma unroll
      for (int n = 0; n < 2; ++n) {
        int col = chh*32 + n*16 + l16;
        bf16x4v tv;
#pragma unroll
        for (int r = 0; r < 4; ++r) {
          int row = w16 + quad*4 + r;
          float val = acc[n][r] + (float)prA[row*S72 + col];
          prO[row*S72 + col] = (bf16)val;
          tv[r] = (bf16)(val * bts_s[col] * gms[col]);
        }
        if (i == 5) *(bf16x4v*)(T2T + col*S72 + w16 + quad*4) = tv;
      }
    }
    __syncthreads();
    pc ^= 1; rc ^= 1;
  }
  bf16* Mrow = rc ? prod1 : prod0;
  bf16* WR   = rc ? prod0 : prod1;

  // VT build from vreg (pow0 region now dead): VT[j][t] = beta_t * v[t][j]
#pragma unroll
  for (int hf = 0; hf < 2; ++hf)
#pragma unroll
    for (int rr = 0; rr < 8; ++rr)
      VT[(hf*64 + lane)*S72 + (r0+rr)] = (bf16)(bts_s[r0+rr] * vreg[hf*8+rr]);
  __syncthreads();

  // V_loc = M (beta V): write V_loc^T
  {
    f32x4 acc[4];
    mm_band<4>(Mrow, VT, w16, chh*64, l16, quad, acc);
#pragma unroll
    for (int n = 0; n < 4; ++n) {
      int col = chh*64 + n*16 + l16;
      bf16x4v tv;
#pragma unroll
      for (int r = 0; r < 4; ++r) tv[r] = (bf16)acc[n][r];
      *(bf16x4v*)(VlT + col*S72 + w16 + quad*4) = tv;
    }
  }
  __syncthreads();

  // dS_loc = Kbar^T V_loc -> global (fp32)
  {
    f32x4 acc[4];
    mm_band<4>(KbT, VlT, w16, chh*64, l16, quad, acc);
#pragma unroll
    for (int n = 0; n < 4; ++n) {
      int col = chh*64 + n*16 + l16;
#pragma unroll
      for (int r = 0; r < 4; ++r)
        dSl[(size_t)bx*8192 + (size_t)(w16 + quad*4 + r)*128 + col] = acc[n][r];
    }
  }
  // W2 = Kbar^T T2 -> WR (bf16 row-major)
  {
    f32x4 acc[2];
    mm_band<2>(KbT, T2T, w16, chh*32, l16, quad, acc);
#pragma unroll
    for (int n = 0; n < 2; ++n) {
      int col = chh*32 + n*16 + l16;
#pragma unroll
      for (int r = 0; r < 4; ++r)
        WR[(w16 + quad*4 + r)*S72 + col] = (bf16)acc[n][r];
    }
  }
  __syncthreads();
  // E = gamma_C I - W2 K -> EF planes 0 (hi) and 1 (lo)
  {
    f32x4 acc[2];
    mm_band<2>(WR, KT, w16, chh*32, l16, quad, acc);
    float gC = gms[63];
    size_t eb = (size_t)bx * 13824;
#pragma unroll
    for (int n = 0; n < 2; ++n) {
      int col = chh*32 + n*16 + l16;
#pragma unroll
      for (int r = 0; r < 4; ++r) {
        int row = w16 + quad*4 + r;
        float ev = ((row == col) ? gC : 0.f) - acc[n][r];
        bf16 eh = (bf16)ev;
        EF[eb + row*S72 + col] = eh;
        EF[eb + 4608 + row*S72 + col] = (bf16)(ev - (float)eh);
      }
    }
  }
  __syncthreads();   // E's reads of WR done before R overwrites
  // R = P T2 -> WR
  {
    f32x4 acc[2];
    mm_band<2>(Pm, T2T, w16, chh*32, l16, quad, acc);
#pragma unroll
    for (int n = 0; n < 2; ++n) {
      int col = chh*32 + n*16 + l16;
#pragma unroll
      for (int r = 0; r < 4; ++r)
        WR[(w16 + quad*4 + r)*S72 + col] = (bf16)acc[n][r];
    }
  }
  __syncthreads();
  // F = diag(gamma) Q - R K -> EF plane 2 (q from qf LDS)
  {
    f32x4 acc[2];
    mm_band<2>(WR, KT, w16, chh*32, l16, quad, acc);
    size_t eb = (size_t)bx * 13824;
#pragma unroll
    for (int n = 0; n < 2; ++n) {
      int col = chh*32 + n*16 + l16;
#pragma unroll
      for (int r = 0; r < 4; ++r) {
        int row = w16 + quad*4 + r;
        float qv = qf[row*68 + col];
        EF[eb + 9216 + row*S72 + col] = (bf16)(gms[row]*qv - acc[n][r]);
      }
    }
  }
  // O_loc = P V_loc -> global
  {
    f32x4 acc[4];
    mm_band<4>(Pm, VlT, w16, chh*64, l16, quad, acc);
#pragma unroll
    for (int n = 0; n < 4; ++n) {
      int col = chh*64 + n*16 + l16;
#pragma unroll
      for (int r = 0; r < 4; ++r)
        obuf[(size_t)(t0 + w16 + quad*4 + r)*2048 + h*128 + col] = acc[n][r];
    }
  }
}

// ---------------- MFMA sequential recurrence + output ----------------
__global__ __launch_bounds__(256) void k_seq(const bf16* __restrict__ EF,
    const float* __restrict__ dSl, float* __restrict__ osb) {
  const int h = blockIdx.x >> 2, dq = blockIdx.x & 3;
  const int tid = threadIdx.x, wave = tid >> 6, lane = tid & 63;
  const int l16 = lane & 15, quad = lane >> 4;
  const int mb = wave * 16;
  __shared__ bf16 ebuf[2][13824];
  __shared__ bf16 Sthi[32*S72], Stlo[32*S72];
  for (int i = tid; i < 2304; i += 256) { Sthi[i] = (bf16)0.f; Stlo[i] = (bf16)0.f; }
  {
    const bf16* efg = EF + (size_t)h * 13824;
    for (int i = tid; i < 1728; i += 256)
      __builtin_amdgcn_global_load_lds(
        (__attribute__((address_space(1))) void*)(efg + i*8),
        (__attribute__((address_space(3))) void*)(&ebuf[0][i*8]), 16, 0, 0);
  }
  float dsv[8];
  {
    size_t base = (size_t)h*8192 + dq*32;
#pragma unroll
    for (int nt = 0; nt < 2; ++nt)
#pragma unroll
      for (int r = 0; r < 4; ++r)
        dsv[nt*4+r] = dSl[base + (size_t)(mb + quad*4 + r)*128 + nt*16 + l16];
  }
  __syncthreads();
#pragma unroll 1
  for (int c = 0; c < 32; ++c) {
    const int cur = c & 1, nxt = cur ^ 1;
    float dsn[8] = {};
    if (c + 1 < 32) {
      const bf16* efg = EF + (size_t)((c+1)*16 + h) * 13824;
      for (int i = tid; i < 1728; i += 256)
        __builtin_amdgcn_global_load_lds(
          (__attribute__((address_space(1))) void*)(efg + i*8),
          (__attribute__((address_space(3))) void*)(&ebuf[nxt][i*8]), 16, 0, 0);
      size_t base = (size_t)((c+1)*16 + h)*8192 + dq*32;
#pragma unroll
      for (int nt = 0; nt < 2; ++nt)
#pragma unroll
        for (int r = 0; r < 4; ++r)
          dsn[nt*4+r] = dSl[base + (size_t)(mb + quad*4 + r)*128 + nt*16 + l16];
    }
    const bf16* Eh = &ebuf[cur][0];
    const bf16* El = &ebuf[cur][4608];
    const bf16* Ff = &ebuf[cur][9216];
    bf16x8 bh[2][2], bl[2][2];
#pragma unroll
    for (int nt = 0; nt < 2; ++nt)
#pragma unroll
      for (int kt = 0; kt < 2; ++kt) {
        bh[nt][kt] = *(const bf16x8*)(Sthi + (nt*16 + l16)*S72 + kt*32 + quad*8);
        bl[nt][kt] = *(const bf16x8*)(Stlo + (nt*16 + l16)*S72 + kt*32 + quad*8);
      }
    f32x4 accS[2], accO[2];
#pragma unroll
    for (int nt = 0; nt < 2; ++nt) {
#pragma unroll
      for (int r = 0; r < 4; ++r) accS[nt][r] = dsv[nt*4+r];
      accO[nt][0]=0.f; accO[nt][1]=0.f; accO[nt][2]=0.f; accO[nt][3]=0.f;
    }
#pragma unroll
    for (int kt = 0; kt < 2; ++kt) {
      bf16x8 aeh = *(const bf16x8*)(Eh + (mb + l16)*S72 + kt*32 + quad*8);
      bf16x8 ael = *(const bf16x8*)(El + (mb + l16)*S72 + kt*32 + quad*8);
      bf16x8 aff = *(const bf16x8*)(Ff + (mb + l16)*S72 + kt*32 + quad*8);
#pragma unroll
      for (int nt = 0; nt < 2; ++nt) {
        accS[nt] = __builtin_amdgcn_mfma_f32_16x16x32_bf16(aeh, bh[nt][kt], accS[nt], 0, 0, 0);
        accS[nt] = __builtin_amdgcn_mfma_f32_16x16x32_bf16(aeh, bl[nt][kt], accS[nt], 0, 0, 0);
        accS[nt] = __builtin_amdgcn_mfma_f32_16x16x32_bf16(ael, bh[nt][kt], accS[nt], 0, 0, 0);
        accO[nt] = __builtin_amdgcn_mfma_f32_16x16x32_bf16(aff, bh[nt][kt], accO[nt], 0, 0, 0);
        accO[nt] = __builtin_amdgcn_mfma_f32_16x16x32_bf16(aff, bl[nt][kt], accO[nt], 0, 0, 0);
      }
    }
    __syncthreads();
    {
      int t0 = c*64;
#pragma unroll
      for (int nt = 0; nt < 2; ++nt)
#pragma unroll
        for (int r = 0; r < 4; ++r)
          osb[(size_t)(t0 + mb + quad*4 + r)*2048 + h*128 + dq*32 + nt*16 + l16] = accO[nt][r];
    }
#pragma unroll
    for (int nt = 0; nt < 2; ++nt) {
      bf16x4v hv, lv;
#pragma unroll
      for (int r = 0; r < 4; ++r) {
        float v = accS[nt][r];
        bf16 hb = (bf16)v;
        hv[r] = hb;
        lv[r] = (bf16)(v - (float)hb);
      }
      *(bf16x4v*)(Sthi + (nt*16 + l16)*S72 + mb + quad*4) = hv;
      *(bf16x4v*)(Stlo + (nt*16 + l16)*S72 + mb + quad*4) = lv;
    }
#pragma unroll
    for (int i = 0; i < 8; ++i) dsv[i] = dsn[i];
    __syncthreads();
  }
}

// ---------------- gated RMSNorm on o = O_loc + O_s, write bf16 ----------------
__global__ __launch_bounds__(64) void k_gatenorm(const float* __restrict__ o,
    const float* __restrict__ os, const float* __restrict__ gpre,
    const float* __restrict__ onw, bf16* __restrict__ og) {
  int t = blockIdx.x, hh = blockIdx.y, lane = threadIdx.x;
  size_t base = (size_t)t*2048 + hh*128 + lane*2;
  float2 o2 = *(const float2*)(o + base);
  float2 s2 = *(const float2*)(os + base);
  o2.x += s2.x; o2.y += s2.y;
  float ss = wredsum(o2.x*o2.x + o2.y*o2.y);
  float rs = rsqrtf(ss * (1.f/128.f) + 1e-5f);
  float2 nw = *(const float2*)(onw + lane*2);
  float2 g2 = *(const float2*)(gpre + base);
  float r0 = o2.x * rs * nw.x * (g2.x * sigmoidf_(g2.x));
  float r1 = o2.y * rs * nw.y * (g2.y * sigmoidf_(g2.y));
  bf16x2v b; b[0] = (bf16)r0; b[1] = (bf16)r1;
  *(bf16x2v*)(og + base) = b;
}

extern "C" void kernel_launch(void* const* d_in, const int* in_sizes, int n_in,
                              void* d_out, int out_size, void* d_ws, size_t ws_size,
                              hipStream_t stream) {
  const float* hs   = (const float*)d_in[0];
  const float* nw   = (const float*)d_in[1];
  const float* qw   = (const float*)d_in[2];
  const float* kw   = (const float*)d_in[3];
  const float* vw   = (const float*)d_in[4];
  const float* aw   = (const float*)d_in[5];
  const float* bw   = (const float*)d_in[6];
  const float* gw   = (const float*)d_in[7];
  const float* dtb  = (const float*)d_in[8];
  const float* alog = (const float*)d_in[9];
  const float* cqw  = (const float*)d_in[10];
  const float* ckw  = (const float*)d_in[11];
  const float* cvw  = (const float*)d_in[12];
  const float* onw  = (const float*)d_in[13];
  const float* opw  = (const float*)d_in[14];
  const float* ow   = (const float*)d_in[15];
  float* out = (float*)d_out;

  char* p = (char*)d_ws;
  auto alloc = [&](size_t bytes) { char* r = p; p += (bytes + 255) & ~255ull; return r; };
  bf16*  xb    = (bf16*) alloc((size_t)2048*1024*2);   // } dSl aliases xb..gwb (16 MB,
  bf16*  qwb   = (bf16*) alloc((size_t)1024*1024*2);   // } all dead after k_gemm_proj)
  bf16*  kwb   = (bf16*) alloc((size_t)1024*1024*2);
  bf16*  vwb   = (bf16*) alloc((size_t)2048*1024*2);
  bf16*  gwb   = (bf16*) alloc((size_t)2048*1024*2);
  bf16*  opwb  = (bf16*) alloc((size_t)1024*2048*2);
  bf16*  owb   = (bf16*) alloc((size_t)1024*1024*2);
  float* qpre  = (float*)alloc((size_t)2048*1024*4);
  float* kpre  = (float*)alloc((size_t)2048*1024*4);
  float* vpre  = (float*)alloc((size_t)2048*2048*4);
  float* gpre  = (float*)alloc((size_t)2048*2048*4);
  float* graw  = (float*)alloc((size_t)2048*16*4);
  float* btb   = (float*)alloc((size_t)2048*16*4);
  float* ob    = (float*)alloc((size_t)2048*2048*4);
  bf16*  ogb   = (bf16*) alloc((size_t)2048*2048*2);
  bf16*  h1b   = (bf16*) alloc((size_t)2048*1024*2);
  bf16*  EF    = (bf16*) alloc((size_t)512*13824*2);
  float* osb   = (float*)alloc((size_t)512*8192*4);
  float* dSl   = (float*)xb;   // 16 MB over xb..gwb (dead after k_gemm_proj)

  k_rmsnorm<<<2048, 256, 0, stream>>>(hs, nw, aw, bw, dtb, alog, xb, graw, btb);
  k_castw<<<4608, 256, 0, stream>>>(qw, kw, vw, gw, opw, ow, qwb, kwb, vwb, gwb, opwb, owb);
  k_gemm_proj<<<dim3(16,16,4), 256, 0, stream>>>(xb, qwb, kwb, vwb, gwb, qpre, kpre, vpre, gpre);
  k_prepass<<<512, 512, 0, stream>>>(qpre, kpre, vpre, cqw, ckw, cvw, graw, btb, EF, dSl, ob);
  k_seq<<<64, 256, 0, stream>>>(EF, dSl, osb);
  k_gatenorm<<<dim3(2048,16,1), 64, 0, stream>>>(ob, osb, gpre, onw, ogb);
  k_gemm_bt<bf16><<<dim3(8,16,1), 256, 0, stream>>>(ogb, opwb, h1b, 1024, 2048);
  k_gemm_bt<float><<<dim3(8,16,1), 256, 0, stream>>>(h1b, owb, out, 1024, 1024);
}